// Round 1
// baseline (5016.233 us; speedup 1.0000x reference)
//
#include <hip/hip_runtime.h>
#include <math.h>

#define B_ 4
#define L_ 2048
#define D_ 1024
#define H_ 16
#define HD_ 64
#define K_ 24
#define MLP_ 4096

// ---------------------------------------------------------------------------
// filters[l,d] = sum_k eig_vecs[l,k] * eig_vals[k]^0.25 * w_filters[k,d]
// ---------------------------------------------------------------------------
__global__ void filters_kernel(const float* __restrict__ eig_vals,
                               const float* __restrict__ eig_vecs,
                               const float* __restrict__ w_filters,
                               float* __restrict__ out) {
    int l = blockIdx.x;
    int d = blockIdx.y * 256 + threadIdx.x;
    __shared__ float r[K_];
    if (threadIdx.x < K_) {
        float ev = eig_vals[threadIdx.x];
        r[threadIdx.x] = eig_vecs[l * K_ + threadIdx.x] * powf(ev, 0.25f);
    }
    __syncthreads();
    float acc = 0.f;
#pragma unroll
    for (int k = 0; k < K_; k++) acc += r[k] * w_filters[k * D_ + d];
    out[(size_t)l * D_ + d] = acc;
}

// ---------------------------------------------------------------------------
// Generic fp32 GEMM: C = act(alpha*A@B + bias) + resid
// A[M,K] row-major, B[K,N] row-major. 128x128 tile, 8x8 micro.
// ---------------------------------------------------------------------------
__device__ __forceinline__ float gelu_t(float x) {
    // tanh-approx gelu: x * sigmoid(2u), overflow-safe
    float u = 0.7978845608028654f * (x + 0.044715f * x * x * x);
    return x / (1.f + __expf(-2.f * u));
}

#define BM 128
#define BN 128
#define BK 16

__global__ __launch_bounds__(256) void gemm_f32(
    const float* __restrict__ A, const float* __restrict__ Bm,
    float* __restrict__ C, int M, int N, int K, float alpha,
    const float* __restrict__ bias, const float* __restrict__ resid, int act) {
    __shared__ float As[BK][BM + 4];  // transposed, padded
    __shared__ float Bs[BK][BN];
    int tid = threadIdx.x;
    int bn = blockIdx.x * BN;
    int bm = blockIdx.y * BM;
    int tx = tid & 15, ty = tid >> 4;
    float acc[8][8];
#pragma unroll
    for (int i = 0; i < 8; i++)
#pragma unroll
        for (int j = 0; j < 8; j++) acc[i][j] = 0.f;

    for (int k0 = 0; k0 < K; k0 += BK) {
#pragma unroll
        for (int q = tid; q < (BM * BK) / 4; q += 256) {
            int r = q >> 2, kk = (q & 3) << 2;
            const float4 v = *(const float4*)&A[(size_t)(bm + r) * K + k0 + kk];
            As[kk + 0][r] = v.x; As[kk + 1][r] = v.y;
            As[kk + 2][r] = v.z; As[kk + 3][r] = v.w;
        }
#pragma unroll
        for (int q = tid; q < (BK * BN) / 4; q += 256) {
            int r = q >> 5, nn = (q & 31) << 2;
            *(float4*)&Bs[r][nn] = *(const float4*)&Bm[(size_t)(k0 + r) * N + bn + nn];
        }
        __syncthreads();
#pragma unroll
        for (int kk = 0; kk < BK; kk++) {
            float a[8], b[8];
            *(float4*)&a[0] = *(float4*)&As[kk][ty * 8];
            *(float4*)&a[4] = *(float4*)&As[kk][ty * 8 + 4];
            *(float4*)&b[0] = *(float4*)&Bs[kk][tx * 8];
            *(float4*)&b[4] = *(float4*)&Bs[kk][tx * 8 + 4];
#pragma unroll
            for (int i = 0; i < 8; i++)
#pragma unroll
                for (int j = 0; j < 8; j++) acc[i][j] += a[i] * b[j];
        }
        __syncthreads();
    }
#pragma unroll
    for (int i = 0; i < 8; i++) {
        size_t row = (size_t)bm + ty * 8 + i;
#pragma unroll
        for (int j4 = 0; j4 < 2; j4++) {
            int col = bn + tx * 8 + j4 * 4;
            float v0 = alpha * acc[i][j4 * 4 + 0];
            float v1 = alpha * acc[i][j4 * 4 + 1];
            float v2 = alpha * acc[i][j4 * 4 + 2];
            float v3 = alpha * acc[i][j4 * 4 + 3];
            if (bias) {
                const float4 bb = *(const float4*)&bias[col];
                v0 += bb.x; v1 += bb.y; v2 += bb.z; v3 += bb.w;
            }
            if (act) {
                v0 = gelu_t(v0); v1 = gelu_t(v1); v2 = gelu_t(v2); v3 = gelu_t(v3);
            }
            if (resid) {
                const float4 rr = *(const float4*)&resid[row * N + col];
                v0 += rr.x; v1 += rr.y; v2 += rr.z; v3 += rr.w;
            }
            float4 o = make_float4(v0, v1, v2, v3);
            *(float4*)&C[row * N + col] = o;
        }
    }
}

// ---------------------------------------------------------------------------
// Causal per-channel conv: out[b,l,d] = sum_{t=0..l} F[t,d]*XI[b,l-t,d]
// Tile: 64 l x 64 d per block (one b). Register sliding-window over t.
// ---------------------------------------------------------------------------
__global__ __launch_bounds__(256) void conv_k(const float* __restrict__ F,
                                              const float* __restrict__ XI,
                                              float* __restrict__ OUT) {
    int l0 = blockIdx.x * 64, d0 = blockIdx.y * 64, b = blockIdx.z;
    __shared__ float fs[64][64];    // [tt][d]
    __shared__ float xs[64][132];   // [d][j_local], j_local in [0,131]
    int tid = threadIdx.x;
    int dd = tid & 63;
    int L0 = (tid >> 6) * 16;       // this thread's first local l
    float acc[16];
#pragma unroll
    for (int i = 0; i < 16; i++) acc[i] = 0.f;
    const float* xib = XI + (size_t)b * L_ * D_;

    for (int t0 = 0; t0 <= l0; t0 += 64) {
        int jb = l0 - t0 - 63;
        // stage filters tile [tt][d]
#pragma unroll
        for (int q = tid; q < 1024; q += 256) {
            int tt = q >> 4, cc = (q & 15) << 2;
            *(float4*)&fs[tt][cc] =
                *(const float4*)&F[(size_t)(t0 + tt) * D_ + d0 + cc];
        }
        // stage xi tile, transposed -> xs[d][jl], zero outside [0,L)
        for (int q = tid; q < 132 * 16; q += 256) {
            int jl = q >> 4, cc = (q & 15) << 2;
            int j = jb + jl;
            float4 v = make_float4(0.f, 0.f, 0.f, 0.f);
            if (j >= 0 && j < L_)
                v = *(const float4*)&xib[(size_t)j * D_ + d0 + cc];
            xs[cc + 0][jl] = v.x; xs[cc + 1][jl] = v.y;
            xs[cc + 2][jl] = v.z; xs[cc + 3][jl] = v.w;
        }
        __syncthreads();

        float w[20];
        {
            float4 t0v = *(const float4*)&xs[dd][L0];
            float4 t1v = *(const float4*)&xs[dd][L0 + 4];
            float4 t2v = *(const float4*)&xs[dd][L0 + 8];
            float4 t3v = *(const float4*)&xs[dd][L0 + 12];
            w[0] = t0v.x; w[1] = t0v.y; w[2] = t0v.z; w[3] = t0v.w;
            w[4] = t1v.x; w[5] = t1v.y; w[6] = t1v.z; w[7] = t1v.w;
            w[8] = t2v.x; w[9] = t2v.y; w[10] = t2v.z; w[11] = t2v.w;
            w[12] = t3v.x; w[13] = t3v.y; w[14] = t3v.z; w[15] = t3v.w;
        }
#pragma unroll
        for (int g4 = 0; g4 < 64; g4 += 4) {
            float4 nx = *(const float4*)&xs[dd][L0 + 16 + g4];
            w[16] = nx.x; w[17] = nx.y; w[18] = nx.z; w[19] = nx.w;
            float f0 = fs[63 - g4][dd];
            float f1 = fs[62 - g4][dd];
            float f2 = fs[61 - g4][dd];
            float f3 = fs[60 - g4][dd];
#pragma unroll
            for (int i = 0; i < 16; i++) acc[i] += f0 * w[i];
#pragma unroll
            for (int i = 0; i < 16; i++) acc[i] += f1 * w[i + 1];
#pragma unroll
            for (int i = 0; i < 16; i++) acc[i] += f2 * w[i + 2];
#pragma unroll
            for (int i = 0; i < 16; i++) acc[i] += f3 * w[i + 3];
#pragma unroll
            for (int i = 0; i < 16; i++) w[i] = w[i + 4];
        }
        __syncthreads();
    }
#pragma unroll
    for (int i = 0; i < 16; i++)
        OUT[((size_t)b * L_ + l0 + L0 + i) * D_ + d0 + dd] = acc[i];
}

// ---------------------------------------------------------------------------
// LayerNorm (row = D_ = 1024), eps 1e-6, population variance
// ---------------------------------------------------------------------------
__global__ __launch_bounds__(256) void layernorm_k(const float* __restrict__ x,
                                                   const float* __restrict__ scale,
                                                   const float* __restrict__ bias,
                                                   float* __restrict__ y) {
    size_t row = blockIdx.x;
    int tid = threadIdx.x;
    const float4 v = *(const float4*)&x[row * D_ + tid * 4];
    float s = v.x + v.y + v.z + v.w;
    float q = v.x * v.x + v.y * v.y + v.z * v.z + v.w * v.w;
#pragma unroll
    for (int off = 32; off >= 1; off >>= 1) {
        s += __shfl_xor(s, off, 64);
        q += __shfl_xor(q, off, 64);
    }
    __shared__ float ss[4], sq[4];
    int w = tid >> 6;
    if ((tid & 63) == 0) { ss[w] = s; sq[w] = q; }
    __syncthreads();
    s = ss[0] + ss[1] + ss[2] + ss[3];
    q = sq[0] + sq[1] + sq[2] + sq[3];
    float mean = s * (1.f / D_);
    float var = q * (1.f / D_) - mean * mean;
    float r = rsqrtf(var + 1e-6f);
    const float4 sc = *(const float4*)&scale[tid * 4];
    const float4 bi = *(const float4*)&bias[tid * 4];
    float4 o;
    o.x = (v.x - mean) * r * sc.x + bi.x;
    o.y = (v.y - mean) * r * sc.y + bi.y;
    o.z = (v.z - mean) * r * sc.z + bi.z;
    o.w = (v.w - mean) * r * sc.w + bi.w;
    *(float4*)&y[row * D_ + tid * 4] = o;
}

// ---------------------------------------------------------------------------
// Flash attention (non-causal), fp32. Q pre-scaled by 1/sqrt(HD).
// Layout [B,L,H,HD]. One block per (q-tile of 64, b*H+h).
// ---------------------------------------------------------------------------
__global__ __launch_bounds__(256) void attn_k(const float* __restrict__ Qp,
                                              const float* __restrict__ Kp,
                                              const float* __restrict__ Vp,
                                              float* __restrict__ Op) {
    int q0 = blockIdx.x * 64;
    int b = blockIdx.y >> 4, h = blockIdx.y & 15;
    __shared__ float qs[64][68];
    __shared__ float ks[64][68];   // reused as P after S-phase
    __shared__ float vs[64][64];
    float (*ps)[68] = ks;
    int tid = threadIdx.x, tx = tid & 15, ty = tid >> 4;
    const size_t bh = ((size_t)b * L_ * H_ + h) * HD_;
    const int lstride = H_ * HD_;  // 1024

#pragma unroll
    for (int qq = tid; qq < 64 * 16; qq += 256) {
        int r = qq >> 4, c = (qq & 15) << 2;
        *(float4*)&qs[r][c] = *(const float4*)&Qp[bh + (size_t)(q0 + r) * lstride + c];
    }
    float m[4], lsum[4], o[4][4];
#pragma unroll
    for (int i = 0; i < 4; i++) {
        m[i] = -1e30f; lsum[i] = 0.f;
#pragma unroll
        for (int j = 0; j < 4; j++) o[i][j] = 0.f;
    }
    __syncthreads();

    for (int s0 = 0; s0 < L_; s0 += 64) {
#pragma unroll
        for (int qq = tid; qq < 64 * 16; qq += 256) {
            int r = qq >> 4, c = (qq & 15) << 2;
            *(float4*)&ks[r][c] = *(const float4*)&Kp[bh + (size_t)(s0 + r) * lstride + c];
            *(float4*)&vs[r][c] = *(const float4*)&Vp[bh + (size_t)(s0 + r) * lstride + c];
        }
        __syncthreads();

        float sv[4][4];
#pragma unroll
        for (int i = 0; i < 4; i++)
#pragma unroll
            for (int j = 0; j < 4; j++) sv[i][j] = 0.f;
#pragma unroll
        for (int c4 = 0; c4 < 16; c4++) {
            float4 qa[4], kb[4];
#pragma unroll
            for (int i = 0; i < 4; i++) qa[i] = *(const float4*)&qs[ty * 4 + i][c4 * 4];
#pragma unroll
            for (int j = 0; j < 4; j++) kb[j] = *(const float4*)&ks[tx * 4 + j][c4 * 4];
#pragma unroll
            for (int i = 0; i < 4; i++)
#pragma unroll
                for (int j = 0; j < 4; j++)
                    sv[i][j] += qa[i].x * kb[j].x + qa[i].y * kb[j].y +
                                qa[i].z * kb[j].z + qa[i].w * kb[j].w;
        }
        // online softmax
        float rm[4], p[4][4], rs[4];
#pragma unroll
        for (int i = 0; i < 4; i++)
            rm[i] = fmaxf(fmaxf(sv[i][0], sv[i][1]), fmaxf(sv[i][2], sv[i][3]));
#pragma unroll
        for (int off = 8; off >= 1; off >>= 1)
#pragma unroll
            for (int i = 0; i < 4; i++) rm[i] = fmaxf(rm[i], __shfl_xor(rm[i], off, 16));
        float cor[4];
#pragma unroll
        for (int i = 0; i < 4; i++) {
            float mn = fmaxf(m[i], rm[i]);
            cor[i] = __expf(m[i] - mn);
            m[i] = mn;
            rs[i] = 0.f;
#pragma unroll
            for (int j = 0; j < 4; j++) {
                p[i][j] = __expf(sv[i][j] - mn);
                rs[i] += p[i][j];
            }
        }
#pragma unroll
        for (int off = 8; off >= 1; off >>= 1)
#pragma unroll
            for (int i = 0; i < 4; i++) rs[i] += __shfl_xor(rs[i], off, 16);
#pragma unroll
        for (int i = 0; i < 4; i++) {
            lsum[i] = lsum[i] * cor[i] + rs[i];
#pragma unroll
            for (int j = 0; j < 4; j++) o[i][j] *= cor[i];
        }
        __syncthreads();  // everyone done reading ks
#pragma unroll
        for (int i = 0; i < 4; i++) {
            float4 pv = make_float4(p[i][0], p[i][1], p[i][2], p[i][3]);
            *(float4*)&ps[ty * 4 + i][tx * 4] = pv;
        }
        __syncthreads();
#pragma unroll
        for (int s = 0; s < 64; s++) {
            float4 v4 = *(const float4*)&vs[s][tx * 4];
#pragma unroll
            for (int i = 0; i < 4; i++) {
                float pp = ps[ty * 4 + i][s];
                o[i][0] += pp * v4.x; o[i][1] += pp * v4.y;
                o[i][2] += pp * v4.z; o[i][3] += pp * v4.w;
            }
        }
        __syncthreads();  // before restaging ks/vs
    }
#pragma unroll
    for (int i = 0; i < 4; i++) {
        float inv = 1.f / lsum[i];
        float4 ov = make_float4(o[i][0] * inv, o[i][1] * inv, o[i][2] * inv, o[i][3] * inv);
        *(float4*)&Op[bh + (size_t)(q0 + ty * 4 + i) * lstride + tx * 4] = ov;
    }
}

// ---------------------------------------------------------------------------
extern "C" void kernel_launch(void* const* d_in, const int* in_sizes, int n_in,
                              void* d_out, int out_size, void* d_ws, size_t ws_size,
                              hipStream_t stream) {
    const float* inputs   = (const float*)d_in[0];
    const float* eig_vals = (const float*)d_in[1];
    const float* eig_vecs = (const float*)d_in[2];
    const float* w_filt   = (const float*)d_in[3];
    const float* w_inp    = (const float*)d_in[4];
    const float* ln1_s    = (const float*)d_in[5];
    const float* ln1_b    = (const float*)d_in[6];
    const float* wq       = (const float*)d_in[7];
    const float* wk       = (const float*)d_in[8];
    const float* wv       = (const float*)d_in[9];
    const float* wo       = (const float*)d_in[10];
    const float* ln2_s    = (const float*)d_in[11];
    const float* ln2_b    = (const float*)d_in[12];
    const float* w1       = (const float*)d_in[13];
    const float* b1       = (const float*)d_in[14];
    const float* w2       = (const float*)d_in[15];
    const float* b2       = (const float*)d_in[16];
    float* out = (float*)d_out;
    char* ws = (char*)d_ws;
    const size_t MB = 1u << 20;
    // region reuse plan (peak 224MB):
    //   0-32MB : STU (long-lived)
    //  32-64MB : XN (ln1 out) -> X (attn residual out)
    //  64-96MB : F (filters, 8MB) -> A (attn out) -> YN (ln2 out)
    //  96-224MB: XI -> Q | K | V -> HID (full 128MB)
    float* STU = (float*)(ws + 0 * MB);
    float* XN  = (float*)(ws + 32 * MB);
    float* Fv  = (float*)(ws + 64 * MB);
    float* XI  = (float*)(ws + 96 * MB);
    float* Qb  = (float*)(ws + 96 * MB);
    float* Kb  = (float*)(ws + 128 * MB);
    float* Vb  = (float*)(ws + 160 * MB);
    float* Ab  = (float*)(ws + 64 * MB);
    float* Xb  = (float*)(ws + 32 * MB);
    float* YN  = (float*)(ws + 64 * MB);
    float* HID = (float*)(ws + 96 * MB);

    const int M = B_ * L_;

    filters_kernel<<<dim3(L_, D_ / 256), 256, 0, stream>>>(eig_vals, eig_vecs, w_filt, Fv);
    gemm_f32<<<dim3(D_ / BN, M / BM), 256, 0, stream>>>(
        inputs, w_inp, XI, M, D_, D_, 1.f, nullptr, nullptr, 0);
    conv_k<<<dim3(L_ / 64, D_ / 64, B_), 256, 0, stream>>>(Fv, XI, STU);
    layernorm_k<<<M, 256, 0, stream>>>(STU, ln1_s, ln1_b, XN);
    gemm_f32<<<dim3(D_ / BN, M / BM), 256, 0, stream>>>(
        XN, wq, Qb, M, D_, D_, 0.125f, nullptr, nullptr, 0);
    gemm_f32<<<dim3(D_ / BN, M / BM), 256, 0, stream>>>(
        XN, wk, Kb, M, D_, D_, 1.f, nullptr, nullptr, 0);
    gemm_f32<<<dim3(D_ / BN, M / BM), 256, 0, stream>>>(
        XN, wv, Vb, M, D_, D_, 1.f, nullptr, nullptr, 0);
    attn_k<<<dim3(L_ / 64, B_ * H_), 256, 0, stream>>>(Qb, Kb, Vb, Ab);
    gemm_f32<<<dim3(D_ / BN, M / BM), 256, 0, stream>>>(
        Ab, wo, Xb, M, D_, D_, 1.f, nullptr, STU, 0);
    layernorm_k<<<M, 256, 0, stream>>>(Xb, ln2_s, ln2_b, YN);
    gemm_f32<<<dim3(MLP_ / BN, M / BM), 256, 0, stream>>>(
        YN, w1, HID, M, MLP_, D_, 1.f, b1, nullptr, 1);
    gemm_f32<<<dim3(D_ / BN, M / BM), 256, 0, stream>>>(
        HID, w2, out, M, D_, MLP_, 1.f, b2, Xb, 0);
}

// Round 2
// 2856.871 us; speedup vs baseline: 1.7558x; 1.7558x over previous
//
#include <hip/hip_runtime.h>
#include <math.h>

#define B_ 4
#define L_ 2048
#define D_ 1024
#define H_ 16
#define HD_ 64
#define K_ 24
#define MLP_ 4096

typedef unsigned short u16;
typedef short s16x8 __attribute__((ext_vector_type(8)));
typedef float fx4 __attribute__((ext_vector_type(4)));

__device__ __forceinline__ u16 f2bf(float f) {
    unsigned u = __float_as_uint(f);
    unsigned r = (u + 0x7fff + ((u >> 16) & 1)) >> 16;
    return (u16)r;
}

__device__ __forceinline__ float gelu_t(float x) {
    float u = 0.7978845608028654f * (x + 0.044715f * x * x * x);
    return x / (1.f + __expf(-2.f * u));
}

__device__ __forceinline__ void gload_lds16(const void* g, void* l) {
    __builtin_amdgcn_global_load_lds(
        (const __attribute__((address_space(1))) unsigned int*)g,
        (__attribute__((address_space(3))) unsigned int*)l, 16, 0, 0);
}

// ---------------------------------------------------------------------------
// filters[l,d] = sum_k eig_vecs[l,k] * eig_vals[k]^0.25 * w_filters[k,d]
// ---------------------------------------------------------------------------
__global__ void filters_kernel(const float* __restrict__ eig_vals,
                               const float* __restrict__ eig_vecs,
                               const float* __restrict__ w_filters,
                               float* __restrict__ out) {
    int l = blockIdx.x;
    int d = blockIdx.y * 256 + threadIdx.x;
    __shared__ float r[K_];
    if (threadIdx.x < K_) {
        float ev = eig_vals[threadIdx.x];
        r[threadIdx.x] = eig_vecs[l * K_ + threadIdx.x] * powf(ev, 0.25f);
    }
    __syncthreads();
    float acc = 0.f;
#pragma unroll
    for (int k = 0; k < K_; k++) acc += r[k] * w_filters[k * D_ + d];
    out[(size_t)l * D_ + d] = acc;
}

// ---------------------------------------------------------------------------
// fp32 -> bf16 elementwise cast (4 elems/thread)
// ---------------------------------------------------------------------------
__global__ __launch_bounds__(256) void cast_bf16(const float* __restrict__ in,
                                                 u16* __restrict__ out) {
    int i = blockIdx.x * 256 + threadIdx.x;
    float4 v = ((const float4*)in)[i];
    ushort4 o;
    o.x = f2bf(v.x); o.y = f2bf(v.y); o.z = f2bf(v.z); o.w = f2bf(v.w);
    ((ushort4*)out)[i] = o;
}

// ---------------------------------------------------------------------------
// fp32 [R][C] -> bf16 [C][R] transpose-cast (32x32 LDS tile)
// ---------------------------------------------------------------------------
__global__ __launch_bounds__(256) void cast_T(const float* __restrict__ in,
                                              u16* __restrict__ out, int R, int C) {
    __shared__ float t[32][33];
    int c0 = blockIdx.x * 32, r0 = blockIdx.y * 32;
    int tx = threadIdx.x & 31, ty = threadIdx.x >> 5;
#pragma unroll
    for (int p = 0; p < 4; p++)
        t[ty + p * 8][tx] = in[(size_t)(r0 + ty + p * 8) * C + c0 + tx];
    __syncthreads();
#pragma unroll
    for (int p = 0; p < 4; p++)
        out[(size_t)(c0 + ty + p * 8) * R + r0 + tx] = f2bf(t[tx][ty + p * 8]);
}

// ---------------------------------------------------------------------------
// bf16 MFMA GEMM: out = act(alpha * A @ Bt^T + bias) + resid
// A[M,K] bf16 row-major, Bt[N,K] bf16 row-major (B transposed).
// Out: fp32 to C if C != null, else bf16 to Cb. 128x128 tile, BK=32.
// LDS fragment-major [kblk][row][8]; global_load_lds width 16.
// ---------------------------------------------------------------------------
__global__ __launch_bounds__(256) void gemm_bf16(
    const u16* __restrict__ A, const u16* __restrict__ Bt,
    float* __restrict__ C, u16* __restrict__ Cb,
    int M, int N, int K, float alpha,
    const float* __restrict__ bias, const float* __restrict__ resid, int act) {
    __shared__ u16 As[4][128][8];
    __shared__ u16 Bs[4][128][8];
    int tid = threadIdx.x;
    int wid = tid >> 6, lane = tid & 63;
    int bm = blockIdx.y * 128, bn = blockIdx.x * 128;
    int wm = (wid >> 1) * 64, wn = (wid & 1) * 64;
    int q = lane >> 4, r = lane & 15;

    const u16* gA0 = A + (size_t)(bm + lane) * K + wid * 8;
    const u16* gA1 = gA0 + (size_t)64 * K;
    const u16* gB0 = Bt + (size_t)(bn + lane) * K + wid * 8;
    const u16* gB1 = gB0 + (size_t)64 * K;
    u16* lA0 = &As[wid][0][0];
    u16* lA1 = &As[wid][64][0];
    u16* lB0 = &Bs[wid][0][0];
    u16* lB1 = &Bs[wid][64][0];
    const u16* pa = &As[q][wm + r][0];
    const u16* pb = &Bs[q][wn + r][0];

    fx4 acc[4][4];
#pragma unroll
    for (int i = 0; i < 4; i++)
#pragma unroll
        for (int j = 0; j < 4; j++) acc[i][j] = (fx4){0.f, 0.f, 0.f, 0.f};

    for (int k0 = 0; k0 < K; k0 += 32) {
        if (k0) __syncthreads();
        gload_lds16(gA0 + k0, lA0);
        gload_lds16(gA1 + k0, lA1);
        gload_lds16(gB0 + k0, lB0);
        gload_lds16(gB1 + k0, lB1);
        __syncthreads();
        s16x8 a[4], b[4];
#pragma unroll
        for (int i = 0; i < 4; i++) a[i] = *(const s16x8*)(pa + i * 128);
#pragma unroll
        for (int j = 0; j < 4; j++) b[j] = *(const s16x8*)(pb + j * 128);
#pragma unroll
        for (int i = 0; i < 4; i++)
#pragma unroll
            for (int j = 0; j < 4; j++)
                acc[i][j] = __builtin_amdgcn_mfma_f32_16x16x32_bf16(
                    a[i], b[j], acc[i][j], 0, 0, 0);
    }

#pragma unroll
    for (int i = 0; i < 4; i++) {
        int row0 = bm + wm + i * 16 + q * 4;
#pragma unroll
        for (int j = 0; j < 4; j++) {
            int col = bn + wn + j * 16 + r;
            float bv = bias ? bias[col] : 0.f;
#pragma unroll
            for (int reg = 0; reg < 4; reg++) {
                float v = alpha * acc[i][j][reg] + bv;
                if (act) v = gelu_t(v);
                size_t idx = (size_t)(row0 + reg) * N + col;
                if (resid) v += resid[idx];
                if (C) C[idx] = v;
                else Cb[idx] = f2bf(v);
            }
        }
    }
}

// ---------------------------------------------------------------------------
// Causal per-channel conv: out[b,l,d] = sum_{t=0..l} F[t,d]*XI[b,l-t,d]
// ---------------------------------------------------------------------------
__global__ __launch_bounds__(256) void conv_k(const float* __restrict__ F,
                                              const float* __restrict__ XI,
                                              float* __restrict__ OUT) {
    int l0 = blockIdx.x * 64, d0 = blockIdx.y * 64, b = blockIdx.z;
    __shared__ float fs[64][64];
    __shared__ float xs[64][132];
    int tid = threadIdx.x;
    int dd = tid & 63;
    int L0 = (tid >> 6) * 16;
    float acc[16];
#pragma unroll
    for (int i = 0; i < 16; i++) acc[i] = 0.f;
    const float* xib = XI + (size_t)b * L_ * D_;

    for (int t0 = 0; t0 <= l0; t0 += 64) {
        int jb = l0 - t0 - 63;
#pragma unroll
        for (int q = tid; q < 1024; q += 256) {
            int tt = q >> 4, cc = (q & 15) << 2;
            *(float4*)&fs[tt][cc] =
                *(const float4*)&F[(size_t)(t0 + tt) * D_ + d0 + cc];
        }
        for (int q = tid; q < 132 * 16; q += 256) {
            int jl = q >> 4, cc = (q & 15) << 2;
            int j = jb + jl;
            float4 v = make_float4(0.f, 0.f, 0.f, 0.f);
            if (j >= 0 && j < L_)
                v = *(const float4*)&xib[(size_t)j * D_ + d0 + cc];
            xs[cc + 0][jl] = v.x; xs[cc + 1][jl] = v.y;
            xs[cc + 2][jl] = v.z; xs[cc + 3][jl] = v.w;
        }
        __syncthreads();

        float w[20];
        {
            float4 t0v = *(const float4*)&xs[dd][L0];
            float4 t1v = *(const float4*)&xs[dd][L0 + 4];
            float4 t2v = *(const float4*)&xs[dd][L0 + 8];
            float4 t3v = *(const float4*)&xs[dd][L0 + 12];
            w[0] = t0v.x; w[1] = t0v.y; w[2] = t0v.z; w[3] = t0v.w;
            w[4] = t1v.x; w[5] = t1v.y; w[6] = t1v.z; w[7] = t1v.w;
            w[8] = t2v.x; w[9] = t2v.y; w[10] = t2v.z; w[11] = t2v.w;
            w[12] = t3v.x; w[13] = t3v.y; w[14] = t3v.z; w[15] = t3v.w;
        }
#pragma unroll
        for (int g4 = 0; g4 < 64; g4 += 4) {
            float4 nx = *(const float4*)&xs[dd][L0 + 16 + g4];
            w[16] = nx.x; w[17] = nx.y; w[18] = nx.z; w[19] = nx.w;
            float f0 = fs[63 - g4][dd];
            float f1 = fs[62 - g4][dd];
            float f2 = fs[61 - g4][dd];
            float f3 = fs[60 - g4][dd];
#pragma unroll
            for (int i = 0; i < 16; i++) acc[i] += f0 * w[i];
#pragma unroll
            for (int i = 0; i < 16; i++) acc[i] += f1 * w[i + 1];
#pragma unroll
            for (int i = 0; i < 16; i++) acc[i] += f2 * w[i + 2];
#pragma unroll
            for (int i = 0; i < 16; i++) acc[i] += f3 * w[i + 3];
#pragma unroll
            for (int i = 0; i < 16; i++) w[i] = w[i + 4];
        }
        __syncthreads();
    }
#pragma unroll
    for (int i = 0; i < 16; i++)
        OUT[((size_t)b * L_ + l0 + L0 + i) * D_ + d0 + dd] = acc[i];
}

// ---------------------------------------------------------------------------
// LayerNorm -> bf16 out (row = 1024), eps 1e-6
// ---------------------------------------------------------------------------
__global__ __launch_bounds__(256) void layernorm_bf16(const float* __restrict__ x,
                                                      const float* __restrict__ scale,
                                                      const float* __restrict__ bias,
                                                      u16* __restrict__ y) {
    size_t row = blockIdx.x;
    int tid = threadIdx.x;
    const float4 v = *(const float4*)&x[row * D_ + tid * 4];
    float s = v.x + v.y + v.z + v.w;
    float q = v.x * v.x + v.y * v.y + v.z * v.z + v.w * v.w;
#pragma unroll
    for (int off = 32; off >= 1; off >>= 1) {
        s += __shfl_xor(s, off, 64);
        q += __shfl_xor(q, off, 64);
    }
    __shared__ float ss[4], sq[4];
    int w = tid >> 6;
    if ((tid & 63) == 0) { ss[w] = s; sq[w] = q; }
    __syncthreads();
    s = ss[0] + ss[1] + ss[2] + ss[3];
    q = sq[0] + sq[1] + sq[2] + sq[3];
    float mean = s * (1.f / D_);
    float var = q * (1.f / D_) - mean * mean;
    float r = rsqrtf(var + 1e-6f);
    const float4 sc = *(const float4*)&scale[tid * 4];
    const float4 bi = *(const float4*)&bias[tid * 4];
    ushort4 o;
    o.x = f2bf((v.x - mean) * r * sc.x + bi.x);
    o.y = f2bf((v.y - mean) * r * sc.y + bi.y);
    o.z = f2bf((v.z - mean) * r * sc.z + bi.z);
    o.w = f2bf((v.w - mean) * r * sc.w + bi.w);
    *(ushort4*)&y[row * D_ + tid * 4] = o;
}

// ---------------------------------------------------------------------------
// Flash attention (non-causal), fp32 in (Q pre-scaled), bf16 out.
// K rows mapped r = tx + 16j  ->  LDS banks tx*4 mod 32 (2-way, free).
// ---------------------------------------------------------------------------
__global__ __launch_bounds__(256) void attn_k(const float* __restrict__ Qp,
                                              const float* __restrict__ Kp,
                                              const float* __restrict__ Vp,
                                              u16* __restrict__ Op) {
    int q0 = blockIdx.x * 64;
    int b = blockIdx.y >> 4, h = blockIdx.y & 15;
    __shared__ float qs[64][68];
    __shared__ float ks[64][68];
    __shared__ float vs[64][64];
    float (*ps)[68] = ks;
    int tid = threadIdx.x, tx = tid & 15, ty = tid >> 4;
    const size_t bh = ((size_t)b * L_ * H_ + h) * HD_;
    const int lstride = H_ * HD_;

#pragma unroll
    for (int qq = tid; qq < 64 * 16; qq += 256) {
        int r = qq >> 4, c = (qq & 15) << 2;
        *(float4*)&qs[r][c] = *(const float4*)&Qp[bh + (size_t)(q0 + r) * lstride + c];
    }
    float m[4], lsum[4], o[4][4];
#pragma unroll
    for (int i = 0; i < 4; i++) {
        m[i] = -1e30f; lsum[i] = 0.f;
#pragma unroll
        for (int j = 0; j < 4; j++) o[i][j] = 0.f;
    }
    __syncthreads();

    for (int s0 = 0; s0 < L_; s0 += 64) {
#pragma unroll
        for (int qq = tid; qq < 64 * 16; qq += 256) {
            int r = qq >> 4, c = (qq & 15) << 2;
            *(float4*)&ks[r][c] = *(const float4*)&Kp[bh + (size_t)(s0 + r) * lstride + c];
            *(float4*)&vs[r][c] = *(const float4*)&Vp[bh + (size_t)(s0 + r) * lstride + c];
        }
        __syncthreads();

        // S = Q K^T ; this thread: q-rows ty*4+i, s-cols tx+16j
        float sv[4][4];
#pragma unroll
        for (int i = 0; i < 4; i++)
#pragma unroll
            for (int j = 0; j < 4; j++) sv[i][j] = 0.f;
#pragma unroll
        for (int c4 = 0; c4 < 16; c4++) {
            float4 qa[4], kb[4];
#pragma unroll
            for (int i = 0; i < 4; i++) qa[i] = *(const float4*)&qs[ty * 4 + i][c4 * 4];
#pragma unroll
            for (int j = 0; j < 4; j++) kb[j] = *(const float4*)&ks[tx + 16 * j][c4 * 4];
#pragma unroll
            for (int i = 0; i < 4; i++)
#pragma unroll
                for (int j = 0; j < 4; j++)
                    sv[i][j] += qa[i].x * kb[j].x + qa[i].y * kb[j].y +
                                qa[i].z * kb[j].z + qa[i].w * kb[j].w;
        }
        // online softmax (row reduction across the 16 tx lanes)
        float rm[4], p[4][4], rs[4];
#pragma unroll
        for (int i = 0; i < 4; i++)
            rm[i] = fmaxf(fmaxf(sv[i][0], sv[i][1]), fmaxf(sv[i][2], sv[i][3]));
#pragma unroll
        for (int off = 8; off >= 1; off >>= 1)
#pragma unroll
            for (int i = 0; i < 4; i++) rm[i] = fmaxf(rm[i], __shfl_xor(rm[i], off, 16));
        float cor[4];
#pragma unroll
        for (int i = 0; i < 4; i++) {
            float mn = fmaxf(m[i], rm[i]);
            cor[i] = __expf(m[i] - mn);
            m[i] = mn;
            rs[i] = 0.f;
#pragma unroll
            for (int j = 0; j < 4; j++) {
                p[i][j] = __expf(sv[i][j] - mn);
                rs[i] += p[i][j];
            }
        }
#pragma unroll
        for (int off = 8; off >= 1; off >>= 1)
#pragma unroll
            for (int i = 0; i < 4; i++) rs[i] += __shfl_xor(rs[i], off, 16);
#pragma unroll
        for (int i = 0; i < 4; i++) {
            lsum[i] = lsum[i] * cor[i] + rs[i];
#pragma unroll
            for (int j = 0; j < 4; j++) o[i][j] *= cor[i];
        }
        __syncthreads();
#pragma unroll
        for (int i = 0; i < 4; i++)
#pragma unroll
            for (int j = 0; j < 4; j++)
                ps[ty * 4 + i][tx + 16 * j] = p[i][j];
        __syncthreads();
        // PV: float4 P rows (broadcast) x float4 V (2-way banks)
#pragma unroll
        for (int s4 = 0; s4 < 16; s4++) {
            float4 pv[4], vv[4];
#pragma unroll
            for (int i = 0; i < 4; i++) pv[i] = *(const float4*)&ps[ty * 4 + i][s4 * 4];
#pragma unroll
            for (int u = 0; u < 4; u++) vv[u] = *(const float4*)&vs[s4 * 4 + u][tx * 4];
#pragma unroll
            for (int i = 0; i < 4; i++) {
                o[i][0] += pv[i].x * vv[0].x + pv[i].y * vv[1].x + pv[i].z * vv[2].x + pv[i].w * vv[3].x;
                o[i][1] += pv[i].x * vv[0].y + pv[i].y * vv[1].y + pv[i].z * vv[2].y + pv[i].w * vv[3].y;
                o[i][2] += pv[i].x * vv[0].z + pv[i].y * vv[1].z + pv[i].z * vv[2].z + pv[i].w * vv[3].z;
                o[i][3] += pv[i].x * vv[0].w + pv[i].y * vv[1].w + pv[i].z * vv[2].w + pv[i].w * vv[3].w;
            }
        }
        __syncthreads();
    }
#pragma unroll
    for (int i = 0; i < 4; i++) {
        float inv = 1.f / lsum[i];
        ushort4 ov;
        ov.x = f2bf(o[i][0] * inv); ov.y = f2bf(o[i][1] * inv);
        ov.z = f2bf(o[i][2] * inv); ov.w = f2bf(o[i][3] * inv);
        *(ushort4*)&Op[bh + (size_t)(q0 + ty * 4 + i) * lstride + tx * 4] = ov;
    }
}

// ---------------------------------------------------------------------------
extern "C" void kernel_launch(void* const* d_in, const int* in_sizes, int n_in,
                              void* d_out, int out_size, void* d_ws, size_t ws_size,
                              hipStream_t stream) {
    const float* inputs   = (const float*)d_in[0];
    const float* eig_vals = (const float*)d_in[1];
    const float* eig_vecs = (const float*)d_in[2];
    const float* w_filt   = (const float*)d_in[3];
    const float* w_inp    = (const float*)d_in[4];
    const float* ln1_s    = (const float*)d_in[5];
    const float* ln1_b    = (const float*)d_in[6];
    const float* wq       = (const float*)d_in[7];
    const float* wk       = (const float*)d_in[8];
    const float* wv       = (const float*)d_in[9];
    const float* wo       = (const float*)d_in[10];
    const float* ln2_s    = (const float*)d_in[11];
    const float* ln2_b    = (const float*)d_in[12];
    const float* w1       = (const float*)d_in[13];
    const float* b1       = (const float*)d_in[14];
    const float* w2       = (const float*)d_in[15];
    const float* b2       = (const float*)d_in[16];
    float* out = (float*)d_out;
    char* ws = (char*)d_ws;
    const size_t MB = 1u << 20;
    // Region plan (peak 224MB):
    //   0-16   : INb (bf16 inputs)            [dead after XI gemm]
    //  16-42   : bf16 transposed weights      [whole launch]
    //  48-80   : XI fp32 -> Q fp32 -> HID(lo)
    //  48-112  : HID bf16 (64MB, after attn)
    //  80-112  : STU fp32                     [dead after WO gemm]
    // 112-128  : XN bf16 -> Ab bf16
    // 128-136  : Fv fp32 -> (K region)
    // 128-160  : K fp32 -> Xb fp32
    // 160-192  : V fp32 -> YN bf16
    u16*   INb  = (u16*)(ws + 0 * MB);
    u16*   WIt  = (u16*)(ws + 16 * MB);
    u16*   WQt  = (u16*)(ws + 18 * MB);
    u16*   WKt  = (u16*)(ws + 20 * MB);
    u16*   WVt  = (u16*)(ws + 22 * MB);
    u16*   WOt  = (u16*)(ws + 24 * MB);
    u16*   W1t  = (u16*)(ws + 26 * MB);
    u16*   W2t  = (u16*)(ws + 34 * MB);
    float* XI   = (float*)(ws + 48 * MB);
    float* Qb   = (float*)(ws + 48 * MB);
    u16*   HID  = (u16*)(ws + 48 * MB);
    float* STU  = (float*)(ws + 80 * MB);
    u16*   XN   = (u16*)(ws + 112 * MB);
    u16*   Ab   = (u16*)(ws + 112 * MB);
    float* Fv   = (float*)(ws + 128 * MB);
    float* Kb   = (float*)(ws + 128 * MB);
    float* Xb   = (float*)(ws + 128 * MB);
    float* Vb   = (float*)(ws + 160 * MB);
    u16*   YN   = (u16*)(ws + 160 * MB);

    const int M = B_ * L_;

    // casts
    cast_bf16<<<(M * D_ / 4 + 255) / 256, 256, 0, stream>>>(inputs, INb);
    cast_T<<<dim3(D_ / 32, D_ / 32), 256, 0, stream>>>(w_inp, WIt, D_, D_);
    cast_T<<<dim3(D_ / 32, D_ / 32), 256, 0, stream>>>(wq, WQt, D_, D_);
    cast_T<<<dim3(D_ / 32, D_ / 32), 256, 0, stream>>>(wk, WKt, D_, D_);
    cast_T<<<dim3(D_ / 32, D_ / 32), 256, 0, stream>>>(wv, WVt, D_, D_);
    cast_T<<<dim3(D_ / 32, D_ / 32), 256, 0, stream>>>(wo, WOt, D_, D_);
    cast_T<<<dim3(MLP_ / 32, D_ / 32), 256, 0, stream>>>(w1, W1t, D_, MLP_);
    cast_T<<<dim3(D_ / 32, MLP_ / 32), 256, 0, stream>>>(w2, W2t, MLP_, D_);

    filters_kernel<<<dim3(L_, D_ / 256), 256, 0, stream>>>(eig_vals, eig_vecs, w_filt, Fv);

    // XI = inputs @ w_inp   (fp32 out for conv)
    gemm_bf16<<<dim3(D_ / 128, M / 128), 256, 0, stream>>>(
        INb, WIt, XI, nullptr, M, D_, D_, 1.f, nullptr, nullptr, 0);
    conv_k<<<dim3(L_ / 64, D_ / 64, B_), 256, 0, stream>>>(Fv, XI, STU);
    layernorm_bf16<<<M, 256, 0, stream>>>(STU, ln1_s, ln1_b, XN);
    // Q,K,V  (fp32 out for fp32 attention; Q pre-scaled)
    gemm_bf16<<<dim3(D_ / 128, M / 128), 256, 0, stream>>>(
        XN, WQt, Qb, nullptr, M, D_, D_, 0.125f, nullptr, nullptr, 0);
    gemm_bf16<<<dim3(D_ / 128, M / 128), 256, 0, stream>>>(
        XN, WKt, Kb, nullptr, M, D_, D_, 1.f, nullptr, nullptr, 0);
    gemm_bf16<<<dim3(D_ / 128, M / 128), 256, 0, stream>>>(
        XN, WVt, Vb, nullptr, M, D_, D_, 1.f, nullptr, nullptr, 0);
    attn_k<<<dim3(L_ / 64, B_ * H_), 256, 0, stream>>>(Qb, Kb, Vb, Ab);
    // X = attn @ wo + STU   (fp32 out)
    gemm_bf16<<<dim3(D_ / 128, M / 128), 256, 0, stream>>>(
        Ab, WOt, Xb, nullptr, M, D_, D_, 1.f, nullptr, STU, 0);
    layernorm_bf16<<<M, 256, 0, stream>>>(Xb, ln2_s, ln2_b, YN);
    // HID = gelu(YN @ w1 + b1)  (bf16 out)
    gemm_bf16<<<dim3(MLP_ / 128, M / 128), 256, 0, stream>>>(
        YN, W1t, nullptr, HID, M, MLP_, D_, 1.f, b1, nullptr, 1);
    // out = HID @ w2 + b2 + Xb  (fp32 out)
    gemm_bf16<<<dim3(D_ / 128, M / 128), 256, 0, stream>>>(
        HID, W2t, out, nullptr, M, D_, MLP_, 1.f, b2, Xb, 0);
}

// Round 3
// 1794.973 us; speedup vs baseline: 2.7946x; 1.5916x over previous
//
#include <hip/hip_runtime.h>
#include <math.h>

#define B_ 4
#define L_ 2048
#define D_ 1024
#define H_ 16
#define HD_ 64
#define K_ 24
#define MLP_ 4096

typedef unsigned short u16;
typedef short s16x8 __attribute__((ext_vector_type(8)));
typedef float fx4 __attribute__((ext_vector_type(4)));

__device__ __forceinline__ u16 f2bf(float f) {
    unsigned u = __float_as_uint(f);
    unsigned r = (u + 0x7fff + ((u >> 16) & 1)) >> 16;
    return (u16)r;
}

__device__ __forceinline__ float gelu_t(float x) {
    float u = 0.7978845608028654f * (x + 0.044715f * x * x * x);
    return x / (1.f + __expf(-2.f * u));
}

__device__ __forceinline__ void gload_lds16(const void* g, void* l) {
    __builtin_amdgcn_global_load_lds(
        (const __attribute__((address_space(1))) unsigned int*)g,
        (__attribute__((address_space(3))) unsigned int*)l, 16, 0, 0);
}

// ---------------------------------------------------------------------------
// filters[l,d] = sum_k eig_vecs[l,k] * eig_vals[k]^0.25 * w_filters[k,d]
// ---------------------------------------------------------------------------
__global__ void filters_kernel(const float* __restrict__ eig_vals,
                               const float* __restrict__ eig_vecs,
                               const float* __restrict__ w_filters,
                               float* __restrict__ out) {
    int l = blockIdx.x;
    int d = blockIdx.y * 256 + threadIdx.x;
    __shared__ float r[K_];
    if (threadIdx.x < K_) {
        float ev = eig_vals[threadIdx.x];
        r[threadIdx.x] = eig_vecs[l * K_ + threadIdx.x] * powf(ev, 0.25f);
    }
    __syncthreads();
    float acc = 0.f;
#pragma unroll
    for (int k = 0; k < K_; k++) acc += r[k] * w_filters[k * D_ + d];
    out[(size_t)l * D_ + d] = acc;
}

// ---------------------------------------------------------------------------
__global__ __launch_bounds__(256) void cast_bf16(const float* __restrict__ in,
                                                 u16* __restrict__ out) {
    int i = blockIdx.x * 256 + threadIdx.x;
    float4 v = ((const float4*)in)[i];
    ushort4 o;
    o.x = f2bf(v.x); o.y = f2bf(v.y); o.z = f2bf(v.z); o.w = f2bf(v.w);
    ((ushort4*)out)[i] = o;
}

// ---------------------------------------------------------------------------
// fp32 [R][C] -> bf16 [C][R] transpose-cast (32x32 LDS tile)
// ---------------------------------------------------------------------------
__global__ __launch_bounds__(256) void cast_T(const float* __restrict__ in,
                                              u16* __restrict__ out, int R, int C) {
    __shared__ float t[32][33];
    int c0 = blockIdx.x * 32, r0 = blockIdx.y * 32;
    int tx = threadIdx.x & 31, ty = threadIdx.x >> 5;
#pragma unroll
    for (int p = 0; p < 4; p++)
        t[ty + p * 8][tx] = in[(size_t)(r0 + ty + p * 8) * C + c0 + tx];
    __syncthreads();
#pragma unroll
    for (int p = 0; p < 4; p++)
        out[(size_t)(c0 + ty + p * 8) * R + r0 + tx] = f2bf(t[tx][ty + p * 8]);
}

// ---------------------------------------------------------------------------
// bf16 MFMA GEMM: out = act(alpha * A @ Bt^T + bias) + resid
// ---------------------------------------------------------------------------
__global__ __launch_bounds__(256) void gemm_bf16(
    const u16* __restrict__ A, const u16* __restrict__ Bt,
    float* __restrict__ C, u16* __restrict__ Cb,
    int M, int N, int K, float alpha,
    const float* __restrict__ bias, const float* __restrict__ resid, int act) {
    __shared__ u16 As[4][128][8];
    __shared__ u16 Bs[4][128][8];
    int tid = threadIdx.x;
    int wid = tid >> 6, lane = tid & 63;
    int bm = blockIdx.y * 128, bn = blockIdx.x * 128;
    int wm = (wid >> 1) * 64, wn = (wid & 1) * 64;
    int q = lane >> 4, r = lane & 15;

    const u16* gA0 = A + (size_t)(bm + lane) * K + wid * 8;
    const u16* gA1 = gA0 + (size_t)64 * K;
    const u16* gB0 = Bt + (size_t)(bn + lane) * K + wid * 8;
    const u16* gB1 = gB0 + (size_t)64 * K;
    u16* lA0 = &As[wid][0][0];
    u16* lA1 = &As[wid][64][0];
    u16* lB0 = &Bs[wid][0][0];
    u16* lB1 = &Bs[wid][64][0];
    const u16* pa = &As[q][wm + r][0];
    const u16* pb = &Bs[q][wn + r][0];

    fx4 acc[4][4];
#pragma unroll
    for (int i = 0; i < 4; i++)
#pragma unroll
        for (int j = 0; j < 4; j++) acc[i][j] = (fx4){0.f, 0.f, 0.f, 0.f};

    for (int k0 = 0; k0 < K; k0 += 32) {
        if (k0) __syncthreads();
        gload_lds16(gA0 + k0, lA0);
        gload_lds16(gA1 + k0, lA1);
        gload_lds16(gB0 + k0, lB0);
        gload_lds16(gB1 + k0, lB1);
        __syncthreads();
        s16x8 a[4], b[4];
#pragma unroll
        for (int i = 0; i < 4; i++) a[i] = *(const s16x8*)(pa + i * 128);
#pragma unroll
        for (int j = 0; j < 4; j++) b[j] = *(const s16x8*)(pb + j * 128);
#pragma unroll
        for (int i = 0; i < 4; i++)
#pragma unroll
            for (int j = 0; j < 4; j++)
                acc[i][j] = __builtin_amdgcn_mfma_f32_16x16x32_bf16(
                    a[i], b[j], acc[i][j], 0, 0, 0);
    }

#pragma unroll
    for (int i = 0; i < 4; i++) {
        int row0 = bm + wm + i * 16 + q * 4;
#pragma unroll
        for (int j = 0; j < 4; j++) {
            int col = bn + wn + j * 16 + r;
            float bv = bias ? bias[col] : 0.f;
#pragma unroll
            for (int reg = 0; reg < 4; reg++) {
                float v = alpha * acc[i][j][reg] + bv;
                if (act) v = gelu_t(v);
                size_t idx = (size_t)(row0 + reg) * N + col;
                if (resid) v += resid[idx];
                if (C) C[idx] = v;
                else Cb[idx] = f2bf(v);
            }
        }
    }
}

// ---------------------------------------------------------------------------
// Causal per-channel conv: out[b,l,d] = sum_{t=0..l} F[t,d]*XI[b,l-t,d]
// ---------------------------------------------------------------------------
__global__ __launch_bounds__(256) void conv_k(const float* __restrict__ F,
                                              const float* __restrict__ XI,
                                              float* __restrict__ OUT) {
    int l0 = blockIdx.x * 64, d0 = blockIdx.y * 64, b = blockIdx.z;
    __shared__ float fs[64][64];
    __shared__ float xs[64][132];
    int tid = threadIdx.x;
    int dd = tid & 63;
    int L0 = (tid >> 6) * 16;
    float acc[16];
#pragma unroll
    for (int i = 0; i < 16; i++) acc[i] = 0.f;
    const float* xib = XI + (size_t)b * L_ * D_;

    for (int t0 = 0; t0 <= l0; t0 += 64) {
        int jb = l0 - t0 - 63;
#pragma unroll
        for (int q = tid; q < 1024; q += 256) {
            int tt = q >> 4, cc = (q & 15) << 2;
            *(float4*)&fs[tt][cc] =
                *(const float4*)&F[(size_t)(t0 + tt) * D_ + d0 + cc];
        }
        for (int q = tid; q < 132 * 16; q += 256) {
            int jl = q >> 4, cc = (q & 15) << 2;
            int j = jb + jl;
            float4 v = make_float4(0.f, 0.f, 0.f, 0.f);
            if (j >= 0 && j < L_)
                v = *(const float4*)&xib[(size_t)j * D_ + d0 + cc];
            xs[cc + 0][jl] = v.x; xs[cc + 1][jl] = v.y;
            xs[cc + 2][jl] = v.z; xs[cc + 3][jl] = v.w;
        }
        __syncthreads();

        float w[20];
        {
            float4 t0v = *(const float4*)&xs[dd][L0];
            float4 t1v = *(const float4*)&xs[dd][L0 + 4];
            float4 t2v = *(const float4*)&xs[dd][L0 + 8];
            float4 t3v = *(const float4*)&xs[dd][L0 + 12];
            w[0] = t0v.x; w[1] = t0v.y; w[2] = t0v.z; w[3] = t0v.w;
            w[4] = t1v.x; w[5] = t1v.y; w[6] = t1v.z; w[7] = t1v.w;
            w[8] = t2v.x; w[9] = t2v.y; w[10] = t2v.z; w[11] = t2v.w;
            w[12] = t3v.x; w[13] = t3v.y; w[14] = t3v.z; w[15] = t3v.w;
        }
#pragma unroll
        for (int g4 = 0; g4 < 64; g4 += 4) {
            float4 nx = *(const float4*)&xs[dd][L0 + 16 + g4];
            w[16] = nx.x; w[17] = nx.y; w[18] = nx.z; w[19] = nx.w;
            float f0 = fs[63 - g4][dd];
            float f1 = fs[62 - g4][dd];
            float f2 = fs[61 - g4][dd];
            float f3 = fs[60 - g4][dd];
#pragma unroll
            for (int i = 0; i < 16; i++) acc[i] += f0 * w[i];
#pragma unroll
            for (int i = 0; i < 16; i++) acc[i] += f1 * w[i + 1];
#pragma unroll
            for (int i = 0; i < 16; i++) acc[i] += f2 * w[i + 2];
#pragma unroll
            for (int i = 0; i < 16; i++) acc[i] += f3 * w[i + 3];
#pragma unroll
            for (int i = 0; i < 16; i++) w[i] = w[i + 4];
        }
        __syncthreads();
    }
#pragma unroll
    for (int i = 0; i < 16; i++)
        OUT[((size_t)b * L_ + l0 + L0 + i) * D_ + d0 + dd] = acc[i];
}

// ---------------------------------------------------------------------------
// LayerNorm -> bf16 out (row = 1024), eps 1e-6
// ---------------------------------------------------------------------------
__global__ __launch_bounds__(256) void layernorm_bf16(const float* __restrict__ x,
                                                      const float* __restrict__ scale,
                                                      const float* __restrict__ bias,
                                                      u16* __restrict__ y) {
    size_t row = blockIdx.x;
    int tid = threadIdx.x;
    const float4 v = *(const float4*)&x[row * D_ + tid * 4];
    float s = v.x + v.y + v.z + v.w;
    float q = v.x * v.x + v.y * v.y + v.z * v.z + v.w * v.w;
#pragma unroll
    for (int off = 32; off >= 1; off >>= 1) {
        s += __shfl_xor(s, off, 64);
        q += __shfl_xor(q, off, 64);
    }
    __shared__ float ss[4], sq[4];
    int w = tid >> 6;
    if ((tid & 63) == 0) { ss[w] = s; sq[w] = q; }
    __syncthreads();
    s = ss[0] + ss[1] + ss[2] + ss[3];
    q = sq[0] + sq[1] + sq[2] + sq[3];
    float mean = s * (1.f / D_);
    float var = q * (1.f / D_) - mean * mean;
    float r = rsqrtf(var + 1e-6f);
    const float4 sc = *(const float4*)&scale[tid * 4];
    const float4 bi = *(const float4*)&bias[tid * 4];
    ushort4 o;
    o.x = f2bf((v.x - mean) * r * sc.x + bi.x);
    o.y = f2bf((v.y - mean) * r * sc.y + bi.y);
    o.z = f2bf((v.z - mean) * r * sc.z + bi.z);
    o.w = f2bf((v.w - mean) * r * sc.w + bi.w);
    *(ushort4*)&y[row * D_ + tid * 4] = o;
}

// ---------------------------------------------------------------------------
// MFMA flash attention (non-causal). Q,K,V bf16 [B,L,H,HD], Q pre-scaled.
// Block: 64 q-rows x one (b,h); 4 waves x 16 q-rows. 16x16x32 bf16 MFMA.
// All LDS rows stride 72 u16 (144B = 16B-aligned; frag b128 reads hit
// uniform 8 accesses/bank = minimum).
// ---------------------------------------------------------------------------
__global__ __launch_bounds__(256) void attn_mfma(const u16* __restrict__ Qg,
                                                 const u16* __restrict__ Kg,
                                                 const u16* __restrict__ Vg,
                                                 u16* __restrict__ Og) {
    int q0 = blockIdx.x * 64;
    int b = blockIdx.y >> 4, h = blockIdx.y & 15;
    __shared__ __align__(16) u16 qs[64 * 72];
    __shared__ __align__(16) u16 ks[64 * 72];
    __shared__ __align__(16) u16 vt[64 * 72];   // V^T: [hd][s]
    __shared__ __align__(16) u16 ps[4][16 * 72];
    int tid = threadIdx.x;
    int w = tid >> 6, lane = tid & 63;
    int quad = lane >> 4, l15 = lane & 15;
    const size_t base = ((size_t)b * L_ * H_ + h) * HD_;
    const int lstride = H_ * HD_;  // 1024

    // stage Q tile (once)
    for (int i = tid; i < 64 * 8; i += 256) {
        int r = i >> 3, cc = i & 7;
        *(uint4*)&qs[r * 72 + cc * 8] =
            *(const uint4*)&Qg[base + (size_t)(q0 + r) * lstride + cc * 8];
    }
    __syncthreads();
    // hoist per-wave Q A-frags (constant over s-loop)
    s16x8 aq[2];
    aq[0] = *(const s16x8*)&qs[(w * 16 + l15) * 72 + quad * 8];
    aq[1] = *(const s16x8*)&qs[(w * 16 + l15) * 72 + 32 + quad * 8];

    float m[4], lsum[4];
    fx4 o[4];
#pragma unroll
    for (int i = 0; i < 4; i++) {
        m[i] = -1e30f; lsum[i] = 0.f;
        o[i] = (fx4){0.f, 0.f, 0.f, 0.f};
    }
    u16* psw = ps[w];

    for (int s0 = 0; s0 < L_; s0 += 64) {
        __syncthreads();  // prior iter's ks/vt reads complete
        // stage K rows (coalesced)
        for (int i = tid; i < 64 * 8; i += 256) {
            int r = i >> 3, cc = i & 7;
            *(uint4*)&ks[r * 72 + cc * 8] =
                *(const uint4*)&Kg[base + (size_t)(s0 + r) * lstride + cc * 8];
        }
        // stage V^T (scattered global 16B loads; conflict-free b16 stores)
        {
            int s = lane;
#pragma unroll
            for (int it = 0; it < 2; it++) {
                int hd0 = w * 8 + it * 32;
                uint4 v = *(const uint4*)&Vg[base + (size_t)(s0 + s) * lstride + hd0];
                u16 tmp[8];
                *(uint4*)tmp = v;
#pragma unroll
                for (int j = 0; j < 8; j++) vt[(hd0 + j) * 72 + s] = tmp[j];
            }
        }
        __syncthreads();

        // S = Q K^T : per-wave 16q x 64s
        fx4 sv[4];
#pragma unroll
        for (int nt = 0; nt < 4; nt++) sv[nt] = (fx4){0.f, 0.f, 0.f, 0.f};
#pragma unroll
        for (int kb = 0; kb < 2; kb++)
#pragma unroll
            for (int nt = 0; nt < 4; nt++) {
                s16x8 bk = *(const s16x8*)&ks[(nt * 16 + l15) * 72 + kb * 32 + quad * 8];
                sv[nt] = __builtin_amdgcn_mfma_f32_16x16x32_bf16(aq[kb], bk, sv[nt], 0, 0, 0);
            }

        // online softmax; lane's rows = quad*4+reg, cols = nt*16+l15
        float mx[4], cor[4], rs[4];
#pragma unroll
        for (int reg = 0; reg < 4; reg++)
            mx[reg] = fmaxf(fmaxf(sv[0][reg], sv[1][reg]), fmaxf(sv[2][reg], sv[3][reg]));
#pragma unroll
        for (int off = 8; off >= 1; off >>= 1)
#pragma unroll
            for (int reg = 0; reg < 4; reg++)
                mx[reg] = fmaxf(mx[reg], __shfl_xor(mx[reg], off, 16));
#pragma unroll
        for (int reg = 0; reg < 4; reg++) {
            float mn = fmaxf(m[reg], mx[reg]);
            cor[reg] = __expf(m[reg] - mn);
            m[reg] = mn;
            rs[reg] = 0.f;
        }
#pragma unroll
        for (int nt = 0; nt < 4; nt++)
#pragma unroll
            for (int reg = 0; reg < 4; reg++) {
                float p = __expf(sv[nt][reg] - m[reg]);
                sv[nt][reg] = p;
                rs[reg] += p;
            }
#pragma unroll
        for (int off = 8; off >= 1; off >>= 1)
#pragma unroll
            for (int reg = 0; reg < 4; reg++)
                rs[reg] += __shfl_xor(rs[reg], off, 16);
#pragma unroll
        for (int reg = 0; reg < 4; reg++) {
            lsum[reg] = lsum[reg] * cor[reg] + rs[reg];
        }
#pragma unroll
        for (int nt = 0; nt < 4; nt++) {
            fx4 on = o[nt];
            on[0] *= cor[0]; on[1] *= cor[1]; on[2] *= cor[2]; on[3] *= cor[3];
            o[nt] = on;
        }
        // P (C/D layout) -> per-wave LDS (A-operand layout source)
#pragma unroll
        for (int nt = 0; nt < 4; nt++)
#pragma unroll
            for (int reg = 0; reg < 4; reg++)
                psw[(quad * 4 + reg) * 72 + nt * 16 + l15] = f2bf(sv[nt][reg]);
        // PV: O += P V   (no barrier: psw is wave-private)
#pragma unroll
        for (int kb = 0; kb < 2; kb++) {
            s16x8 ap = *(const s16x8*)&psw[l15 * 72 + kb * 32 + quad * 8];
#pragma unroll
            for (int nt = 0; nt < 4; nt++) {
                s16x8 bv = *(const s16x8*)&vt[(nt * 16 + l15) * 72 + kb * 32 + quad * 8];
                o[nt] = __builtin_amdgcn_mfma_f32_16x16x32_bf16(ap, bv, o[nt], 0, 0, 0);
            }
        }
    }
    // epilogue: O / l -> bf16 out
#pragma unroll
    for (int reg = 0; reg < 4; reg++) {
        float inv = 1.f / lsum[reg];
        size_t row = base + (size_t)(q0 + w * 16 + quad * 4 + reg) * lstride;
#pragma unroll
        for (int nt = 0; nt < 4; nt++)
            Og[row + nt * 16 + l15] = f2bf(o[nt][reg] * inv);
    }
}

// ---------------------------------------------------------------------------
extern "C" void kernel_launch(void* const* d_in, const int* in_sizes, int n_in,
                              void* d_out, int out_size, void* d_ws, size_t ws_size,
                              hipStream_t stream) {
    const float* inputs   = (const float*)d_in[0];
    const float* eig_vals = (const float*)d_in[1];
    const float* eig_vecs = (const float*)d_in[2];
    const float* w_filt   = (const float*)d_in[3];
    const float* w_inp    = (const float*)d_in[4];
    const float* ln1_s    = (const float*)d_in[5];
    const float* ln1_b    = (const float*)d_in[6];
    const float* wq       = (const float*)d_in[7];
    const float* wk       = (const float*)d_in[8];
    const float* wv       = (const float*)d_in[9];
    const float* wo       = (const float*)d_in[10];
    const float* ln2_s    = (const float*)d_in[11];
    const float* ln2_b    = (const float*)d_in[12];
    const float* w1       = (const float*)d_in[13];
    const float* b1       = (const float*)d_in[14];
    const float* w2       = (const float*)d_in[15];
    const float* b2       = (const float*)d_in[16];
    float* out = (float*)d_out;
    char* ws = (char*)d_ws;
    const size_t MB = 1u << 20;
    // Region plan:
    //   0-16   : INb (bf16 inputs)            [dead after XI gemm]
    //  16-42   : bf16 transposed weights      [whole launch]
    //  48-64   : Qb bf16 -> HID(lo)
    //  48-112  : HID bf16 (64MB, MLP phase)
    //  80-112  : STU fp32                     [dead after WO gemm]
    // 112-128  : XN bf16 -> Ab bf16
    // 128-136  : Fv fp32 -> Kb bf16 region
    // 128-144  : Kb bf16 -> Xb fp32 (128-160)
    // 160-176  : Vb bf16 -> YN bf16
    // 176-208  : XI fp32 [dead after conv]
    u16*   INb  = (u16*)(ws + 0 * MB);
    u16*   WIt  = (u16*)(ws + 16 * MB);
    u16*   WQt  = (u16*)(ws + 18 * MB);
    u16*   WKt  = (u16*)(ws + 20 * MB);
    u16*   WVt  = (u16*)(ws + 22 * MB);
    u16*   WOt  = (u16*)(ws + 24 * MB);
    u16*   W1t  = (u16*)(ws + 26 * MB);
    u16*   W2t  = (u16*)(ws + 34 * MB);
    u16*   Qb   = (u16*)(ws + 48 * MB);
    u16*   HID  = (u16*)(ws + 48 * MB);
    float* STU  = (float*)(ws + 80 * MB);
    u16*   XN   = (u16*)(ws + 112 * MB);
    u16*   Ab   = (u16*)(ws + 112 * MB);
    float* Fv   = (float*)(ws + 128 * MB);
    u16*   Kb   = (u16*)(ws + 128 * MB);
    float* Xb   = (float*)(ws + 128 * MB);
    u16*   Vb   = (u16*)(ws + 160 * MB);
    u16*   YN   = (u16*)(ws + 160 * MB);
    float* XI   = (float*)(ws + 176 * MB);

    const int M = B_ * L_;

    // casts
    cast_bf16<<<(M * D_ / 4 + 255) / 256, 256, 0, stream>>>(inputs, INb);
    cast_T<<<dim3(D_ / 32, D_ / 32), 256, 0, stream>>>(w_inp, WIt, D_, D_);
    cast_T<<<dim3(D_ / 32, D_ / 32), 256, 0, stream>>>(wq, WQt, D_, D_);
    cast_T<<<dim3(D_ / 32, D_ / 32), 256, 0, stream>>>(wk, WKt, D_, D_);
    cast_T<<<dim3(D_ / 32, D_ / 32), 256, 0, stream>>>(wv, WVt, D_, D_);
    cast_T<<<dim3(D_ / 32, D_ / 32), 256, 0, stream>>>(wo, WOt, D_, D_);
    cast_T<<<dim3(MLP_ / 32, D_ / 32), 256, 0, stream>>>(w1, W1t, D_, MLP_);
    cast_T<<<dim3(D_ / 32, MLP_ / 32), 256, 0, stream>>>(w2, W2t, MLP_, D_);

    filters_kernel<<<dim3(L_, D_ / 256), 256, 0, stream>>>(eig_vals, eig_vecs, w_filt, Fv);

    // XI = inputs @ w_inp   (fp32 out for conv)
    gemm_bf16<<<dim3(D_ / 128, M / 128), 256, 0, stream>>>(
        INb, WIt, XI, nullptr, M, D_, D_, 1.f, nullptr, nullptr, 0);
    conv_k<<<dim3(L_ / 64, D_ / 64, B_), 256, 0, stream>>>(Fv, XI, STU);
    layernorm_bf16<<<M, 256, 0, stream>>>(STU, ln1_s, ln1_b, XN);
    // Q,K,V in bf16 (Q pre-scaled by 1/sqrt(64))
    gemm_bf16<<<dim3(D_ / 128, M / 128), 256, 0, stream>>>(
        XN, WQt, nullptr, Qb, M, D_, D_, 0.125f, nullptr, nullptr, 0);
    gemm_bf16<<<dim3(D_ / 128, M / 128), 256, 0, stream>>>(
        XN, WKt, nullptr, Kb, M, D_, D_, 1.f, nullptr, nullptr, 0);
    gemm_bf16<<<dim3(D_ / 128, M / 128), 256, 0, stream>>>(
        XN, WVt, nullptr, Vb, M, D_, D_, 1.f, nullptr, nullptr, 0);
    attn_mfma<<<dim3(L_ / 64, B_ * H_), 256, 0, stream>>>(Qb, Kb, Vb, Ab);
    // X = attn @ wo + STU   (fp32 out)
    gemm_bf16<<<dim3(D_ / 128, M / 128), 256, 0, stream>>>(
        Ab, WOt, Xb, nullptr, M, D_, D_, 1.f, nullptr, STU, 0);
    layernorm_bf16<<<M, 256, 0, stream>>>(Xb, ln2_s, ln2_b, YN);
    // HID = gelu(YN @ w1 + b1)  (bf16 out)
    gemm_bf16<<<dim3(MLP_ / 128, M / 128), 256, 0, stream>>>(
        YN, W1t, nullptr, HID, M, MLP_, D_, 1.f, b1, nullptr, 1);
    // out = HID @ w2 + b2 + Xb  (fp32 out)
    gemm_bf16<<<dim3(D_ / 128, M / 128), 256, 0, stream>>>(
        HID, W2t, out, nullptr, M, D_, MLP_, 1.f, b2, Xb, 0);
}

// Round 4
// 1347.294 us; speedup vs baseline: 3.7232x; 1.3323x over previous
//
#include <hip/hip_runtime.h>
#include <math.h>

#define B_ 4
#define L_ 2048
#define D_ 1024
#define H_ 16
#define HD_ 64
#define K_ 24
#define MLP_ 4096

typedef unsigned short u16;
typedef short s16x8 __attribute__((ext_vector_type(8)));
typedef float fx4 __attribute__((ext_vector_type(4)));

__device__ __forceinline__ u16 f2bf(float f) {
    unsigned u = __float_as_uint(f);
    unsigned r = (u + 0x7fff + ((u >> 16) & 1)) >> 16;
    return (u16)r;
}

__device__ __forceinline__ float gelu_t(float x) {
    float u = 0.7978845608028654f * (x + 0.044715f * x * x * x);
    return x / (1.f + __expf(-2.f * u));
}

__device__ __forceinline__ void gload_lds16(const void* g, void* l) {
    __builtin_amdgcn_global_load_lds(
        (const __attribute__((address_space(1))) unsigned int*)g,
        (__attribute__((address_space(3))) unsigned int*)l, 16, 0, 0);
}

// ---------------------------------------------------------------------------
// filters[l,d] = sum_k eig_vecs[l,k] * eig_vals[k]^0.25 * w_filters[k,d]
// ---------------------------------------------------------------------------
__global__ void filters_kernel(const float* __restrict__ eig_vals,
                               const float* __restrict__ eig_vecs,
                               const float* __restrict__ w_filters,
                               float* __restrict__ out) {
    int l = blockIdx.x;
    int d = blockIdx.y * 256 + threadIdx.x;
    __shared__ float r[K_];
    if (threadIdx.x < K_) {
        float ev = eig_vals[threadIdx.x];
        r[threadIdx.x] = eig_vecs[l * K_ + threadIdx.x] * powf(ev, 0.25f);
    }
    __syncthreads();
    float acc = 0.f;
#pragma unroll
    for (int k = 0; k < K_; k++) acc += r[k] * w_filters[k * D_ + d];
    out[(size_t)l * D_ + d] = acc;
}

// ---------------------------------------------------------------------------
__global__ __launch_bounds__(256) void cast_bf16(const float* __restrict__ in,
                                                 u16* __restrict__ out) {
    int i = blockIdx.x * 256 + threadIdx.x;
    float4 v = ((const float4*)in)[i];
    ushort4 o;
    o.x = f2bf(v.x); o.y = f2bf(v.y); o.z = f2bf(v.z); o.w = f2bf(v.w);
    ((ushort4*)out)[i] = o;
}

// ---------------------------------------------------------------------------
// fp32 [R][C] -> bf16 [C][R] transpose-cast (32x32 LDS tile)
// ---------------------------------------------------------------------------
__global__ __launch_bounds__(256) void cast_T(const float* __restrict__ in,
                                              u16* __restrict__ out, int R, int C) {
    __shared__ float t[32][33];
    int c0 = blockIdx.x * 32, r0 = blockIdx.y * 32;
    int tx = threadIdx.x & 31, ty = threadIdx.x >> 5;
#pragma unroll
    for (int p = 0; p < 4; p++)
        t[ty + p * 8][tx] = in[(size_t)(r0 + ty + p * 8) * C + c0 + tx];
    __syncthreads();
#pragma unroll
    for (int p = 0; p < 4; p++)
        out[(size_t)(c0 + ty + p * 8) * R + r0 + tx] = f2bf(t[tx][ty + p * 8]);
}

// ---------------------------------------------------------------------------
// bf16 MFMA GEMM: out = act(alpha * A @ Bt^T + bias) + resid
// ---------------------------------------------------------------------------
__global__ __launch_bounds__(256) void gemm_bf16(
    const u16* __restrict__ A, const u16* __restrict__ Bt,
    float* __restrict__ C, u16* __restrict__ Cb,
    int M, int N, int K, float alpha,
    const float* __restrict__ bias, const float* __restrict__ resid, int act) {
    __shared__ u16 As[4][128][8];
    __shared__ u16 Bs[4][128][8];
    int tid = threadIdx.x;
    int wid = tid >> 6, lane = tid & 63;
    int bm = blockIdx.y * 128, bn = blockIdx.x * 128;
    int wm = (wid >> 1) * 64, wn = (wid & 1) * 64;
    int q = lane >> 4, r = lane & 15;

    const u16* gA0 = A + (size_t)(bm + lane) * K + wid * 8;
    const u16* gA1 = gA0 + (size_t)64 * K;
    const u16* gB0 = Bt + (size_t)(bn + lane) * K + wid * 8;
    const u16* gB1 = gB0 + (size_t)64 * K;
    u16* lA0 = &As[wid][0][0];
    u16* lA1 = &As[wid][64][0];
    u16* lB0 = &Bs[wid][0][0];
    u16* lB1 = &Bs[wid][64][0];
    const u16* pa = &As[q][wm + r][0];
    const u16* pb = &Bs[q][wn + r][0];

    fx4 acc[4][4];
#pragma unroll
    for (int i = 0; i < 4; i++)
#pragma unroll
        for (int j = 0; j < 4; j++) acc[i][j] = (fx4){0.f, 0.f, 0.f, 0.f};

    for (int k0 = 0; k0 < K; k0 += 32) {
        if (k0) __syncthreads();
        gload_lds16(gA0 + k0, lA0);
        gload_lds16(gA1 + k0, lA1);
        gload_lds16(gB0 + k0, lB0);
        gload_lds16(gB1 + k0, lB1);
        __syncthreads();
        s16x8 a[4], b[4];
#pragma unroll
        for (int i = 0; i < 4; i++) a[i] = *(const s16x8*)(pa + i * 128);
#pragma unroll
        for (int j = 0; j < 4; j++) b[j] = *(const s16x8*)(pb + j * 128);
#pragma unroll
        for (int i = 0; i < 4; i++)
#pragma unroll
            for (int j = 0; j < 4; j++)
                acc[i][j] = __builtin_amdgcn_mfma_f32_16x16x32_bf16(
                    a[i], b[j], acc[i][j], 0, 0, 0);
    }

#pragma unroll
    for (int i = 0; i < 4; i++) {
        int row0 = bm + wm + i * 16 + q * 4;
#pragma unroll
        for (int j = 0; j < 4; j++) {
            int col = bn + wn + j * 16 + r;
            float bv = bias ? bias[col] : 0.f;
#pragma unroll
            for (int reg = 0; reg < 4; reg++) {
                float v = alpha * acc[i][j][reg] + bv;
                if (act) v = gelu_t(v);
                size_t idx = (size_t)(row0 + reg) * N + col;
                if (resid) v += resid[idx];
                if (C) C[idx] = v;
                else Cb[idx] = f2bf(v);
            }
        }
    }
}

// ---------------------------------------------------------------------------
// Causal per-channel conv: out[b,l,d] = sum_{t=0..l} F[t,d]*XI[b,l-t,d]
// Balanced: block x = pair index i, handles l-tiles i and 31-i -> every
// block does exactly 33 K-iterations. xs stride 133 (odd) -> all LDS
// access patterns <=2-way (free).
// ---------------------------------------------------------------------------
__global__ __launch_bounds__(256) void conv_k(const float* __restrict__ F,
                                              const float* __restrict__ XI,
                                              float* __restrict__ OUT) {
    int d0 = blockIdx.y * 64, b = blockIdx.z;
    __shared__ float fs[64][64];
    __shared__ float xs[64][133];
    int tid = threadIdx.x;
    int dd = tid & 63;
    int L0 = (tid >> 6) * 16;
    const float* xib = XI + (size_t)b * L_ * D_;

#pragma unroll
    for (int half = 0; half < 2; half++) {
        int lt = half ? (31 - blockIdx.x) : blockIdx.x;
        int l0 = lt * 64;
        float acc[16];
#pragma unroll
        for (int i = 0; i < 16; i++) acc[i] = 0.f;

        for (int t0 = 0; t0 <= l0; t0 += 64) {
            int jb = l0 - t0 - 63;
#pragma unroll
            for (int q = tid; q < 1024; q += 256) {
                int tt = q >> 4, cc = (q & 15) << 2;
                *(float4*)&fs[tt][cc] =
                    *(const float4*)&F[(size_t)(t0 + tt) * D_ + d0 + cc];
            }
            for (int q = tid; q < 132 * 16; q += 256) {
                int jl = q >> 4, cc = (q & 15) << 2;
                int j = jb + jl;
                float4 v = make_float4(0.f, 0.f, 0.f, 0.f);
                if (j >= 0 && j < L_)
                    v = *(const float4*)&xib[(size_t)j * D_ + d0 + cc];
                xs[cc + 0][jl] = v.x; xs[cc + 1][jl] = v.y;
                xs[cc + 2][jl] = v.z; xs[cc + 3][jl] = v.w;
            }
            __syncthreads();

            float w[20];
            {
                float4 t0v = *(const float4*)&xs[dd][L0];
                float4 t1v = *(const float4*)&xs[dd][L0 + 4];
                float4 t2v = *(const float4*)&xs[dd][L0 + 8];
                float4 t3v = *(const float4*)&xs[dd][L0 + 12];
                w[0] = t0v.x; w[1] = t0v.y; w[2] = t0v.z; w[3] = t0v.w;
                w[4] = t1v.x; w[5] = t1v.y; w[6] = t1v.z; w[7] = t1v.w;
                w[8] = t2v.x; w[9] = t2v.y; w[10] = t2v.z; w[11] = t2v.w;
                w[12] = t3v.x; w[13] = t3v.y; w[14] = t3v.z; w[15] = t3v.w;
            }
#pragma unroll
            for (int g4 = 0; g4 < 64; g4 += 4) {
                float4 nx = *(const float4*)&xs[dd][L0 + 16 + g4];
                w[16] = nx.x; w[17] = nx.y; w[18] = nx.z; w[19] = nx.w;
                float f0 = fs[63 - g4][dd];
                float f1 = fs[62 - g4][dd];
                float f2 = fs[61 - g4][dd];
                float f3 = fs[60 - g4][dd];
#pragma unroll
                for (int i = 0; i < 16; i++) acc[i] += f0 * w[i];
#pragma unroll
                for (int i = 0; i < 16; i++) acc[i] += f1 * w[i + 1];
#pragma unroll
                for (int i = 0; i < 16; i++) acc[i] += f2 * w[i + 2];
#pragma unroll
                for (int i = 0; i < 16; i++) acc[i] += f3 * w[i + 3];
#pragma unroll
                for (int i = 0; i < 16; i++) w[i] = w[i + 4];
            }
            __syncthreads();
        }
#pragma unroll
        for (int i = 0; i < 16; i++)
            OUT[((size_t)b * L_ + l0 + L0 + i) * D_ + d0 + dd] = acc[i];
    }
}

// ---------------------------------------------------------------------------
// LayerNorm -> bf16 out (row = 1024), eps 1e-6
// ---------------------------------------------------------------------------
__global__ __launch_bounds__(256) void layernorm_bf16(const float* __restrict__ x,
                                                      const float* __restrict__ scale,
                                                      const float* __restrict__ bias,
                                                      u16* __restrict__ y) {
    size_t row = blockIdx.x;
    int tid = threadIdx.x;
    const float4 v = *(const float4*)&x[row * D_ + tid * 4];
    float s = v.x + v.y + v.z + v.w;
    float q = v.x * v.x + v.y * v.y + v.z * v.z + v.w * v.w;
#pragma unroll
    for (int off = 32; off >= 1; off >>= 1) {
        s += __shfl_xor(s, off, 64);
        q += __shfl_xor(q, off, 64);
    }
    __shared__ float ss[4], sq[4];
    int w = tid >> 6;
    if ((tid & 63) == 0) { ss[w] = s; sq[w] = q; }
    __syncthreads();
    s = ss[0] + ss[1] + ss[2] + ss[3];
    q = sq[0] + sq[1] + sq[2] + sq[3];
    float mean = s * (1.f / D_);
    float var = q * (1.f / D_) - mean * mean;
    float r = rsqrtf(var + 1e-6f);
    const float4 sc = *(const float4*)&scale[tid * 4];
    const float4 bi = *(const float4*)&bias[tid * 4];
    ushort4 o;
    o.x = f2bf((v.x - mean) * r * sc.x + bi.x);
    o.y = f2bf((v.y - mean) * r * sc.y + bi.y);
    o.z = f2bf((v.z - mean) * r * sc.z + bi.z);
    o.w = f2bf((v.w - mean) * r * sc.w + bi.w);
    *(ushort4*)&y[row * D_ + tid * 4] = o;
}

// ---------------------------------------------------------------------------
// MFMA flash attention (non-causal). Q,K,V bf16 [B,L,H,HD], Q pre-scaled.
// ---------------------------------------------------------------------------
__global__ __launch_bounds__(256) void attn_mfma(const u16* __restrict__ Qg,
                                                 const u16* __restrict__ Kg,
                                                 const u16* __restrict__ Vg,
                                                 u16* __restrict__ Og) {
    int q0 = blockIdx.x * 64;
    int b = blockIdx.y >> 4, h = blockIdx.y & 15;
    __shared__ __align__(16) u16 qs[64 * 72];
    __shared__ __align__(16) u16 ks[64 * 72];
    __shared__ __align__(16) u16 vt[64 * 72];   // V^T: [hd][s]
    __shared__ __align__(16) u16 ps[4][16 * 72];
    int tid = threadIdx.x;
    int w = tid >> 6, lane = tid & 63;
    int quad = lane >> 4, l15 = lane & 15;
    const size_t base = ((size_t)b * L_ * H_ + h) * HD_;
    const int lstride = H_ * HD_;  // 1024

    // stage Q tile (once)
    for (int i = tid; i < 64 * 8; i += 256) {
        int r = i >> 3, cc = i & 7;
        *(uint4*)&qs[r * 72 + cc * 8] =
            *(const uint4*)&Qg[base + (size_t)(q0 + r) * lstride + cc * 8];
    }
    __syncthreads();
    s16x8 aq[2];
    aq[0] = *(const s16x8*)&qs[(w * 16 + l15) * 72 + quad * 8];
    aq[1] = *(const s16x8*)&qs[(w * 16 + l15) * 72 + 32 + quad * 8];

    float m[4], lsum[4];
    fx4 o[4];
#pragma unroll
    for (int i = 0; i < 4; i++) {
        m[i] = -1e30f; lsum[i] = 0.f;
        o[i] = (fx4){0.f, 0.f, 0.f, 0.f};
    }
    u16* psw = ps[w];

    for (int s0 = 0; s0 < L_; s0 += 64) {
        __syncthreads();
        for (int i = tid; i < 64 * 8; i += 256) {
            int r = i >> 3, cc = i & 7;
            *(uint4*)&ks[r * 72 + cc * 8] =
                *(const uint4*)&Kg[base + (size_t)(s0 + r) * lstride + cc * 8];
        }
        {
            int s = lane;
#pragma unroll
            for (int it = 0; it < 2; it++) {
                int hd0 = w * 8 + it * 32;
                uint4 v = *(const uint4*)&Vg[base + (size_t)(s0 + s) * lstride + hd0];
                u16 tmp[8];
                *(uint4*)tmp = v;
#pragma unroll
                for (int j = 0; j < 8; j++) vt[(hd0 + j) * 72 + s] = tmp[j];
            }
        }
        __syncthreads();

        fx4 sv[4];
#pragma unroll
        for (int nt = 0; nt < 4; nt++) sv[nt] = (fx4){0.f, 0.f, 0.f, 0.f};
#pragma unroll
        for (int kb = 0; kb < 2; kb++)
#pragma unroll
            for (int nt = 0; nt < 4; nt++) {
                s16x8 bk = *(const s16x8*)&ks[(nt * 16 + l15) * 72 + kb * 32 + quad * 8];
                sv[nt] = __builtin_amdgcn_mfma_f32_16x16x32_bf16(aq[kb], bk, sv[nt], 0, 0, 0);
            }

        float mx[4], cor[4], rs[4];
#pragma unroll
        for (int reg = 0; reg < 4; reg++)
            mx[reg] = fmaxf(fmaxf(sv[0][reg], sv[1][reg]), fmaxf(sv[2][reg], sv[3][reg]));
#pragma unroll
        for (int off = 8; off >= 1; off >>= 1)
#pragma unroll
            for (int reg = 0; reg < 4; reg++)
                mx[reg] = fmaxf(mx[reg], __shfl_xor(mx[reg], off, 16));
#pragma unroll
        for (int reg = 0; reg < 4; reg++) {
            float mn = fmaxf(m[reg], mx[reg]);
            cor[reg] = __expf(m[reg] - mn);
            m[reg] = mn;
            rs[reg] = 0.f;
        }
#pragma unroll
        for (int nt = 0; nt < 4; nt++)
#pragma unroll
            for (int reg = 0; reg < 4; reg++) {
                float p = __expf(sv[nt][reg] - m[reg]);
                sv[nt][reg] = p;
                rs[reg] += p;
            }
#pragma unroll
        for (int off = 8; off >= 1; off >>= 1)
#pragma unroll
            for (int reg = 0; reg < 4; reg++)
                rs[reg] += __shfl_xor(rs[reg], off, 16);
#pragma unroll
        for (int reg = 0; reg < 4; reg++) {
            lsum[reg] = lsum[reg] * cor[reg] + rs[reg];
        }
#pragma unroll
        for (int nt = 0; nt < 4; nt++) {
            fx4 on = o[nt];
            on[0] *= cor[0]; on[1] *= cor[1]; on[2] *= cor[2]; on[3] *= cor[3];
            o[nt] = on;
        }
#pragma unroll
        for (int nt = 0; nt < 4; nt++)
#pragma unroll
            for (int reg = 0; reg < 4; reg++)
                psw[(quad * 4 + reg) * 72 + nt * 16 + l15] = f2bf(sv[nt][reg]);
#pragma unroll
        for (int kb = 0; kb < 2; kb++) {
            s16x8 ap = *(const s16x8*)&psw[l15 * 72 + kb * 32 + quad * 8];
#pragma unroll
            for (int nt = 0; nt < 4; nt++) {
                s16x8 bv = *(const s16x8*)&vt[(nt * 16 + l15) * 72 + kb * 32 + quad * 8];
                o[nt] = __builtin_amdgcn_mfma_f32_16x16x32_bf16(ap, bv, o[nt], 0, 0, 0);
            }
        }
    }
#pragma unroll
    for (int reg = 0; reg < 4; reg++) {
        float inv = 1.f / lsum[reg];
        size_t row = base + (size_t)(q0 + w * 16 + quad * 4 + reg) * lstride;
#pragma unroll
        for (int nt = 0; nt < 4; nt++)
            Og[row + nt * 16 + l15] = f2bf(o[nt][reg] * inv);
    }
}

// ---------------------------------------------------------------------------
extern "C" void kernel_launch(void* const* d_in, const int* in_sizes, int n_in,
                              void* d_out, int out_size, void* d_ws, size_t ws_size,
                              hipStream_t stream) {
    const float* inputs   = (const float*)d_in[0];
    const float* eig_vals = (const float*)d_in[1];
    const float* eig_vecs = (const float*)d_in[2];
    const float* w_filt   = (const float*)d_in[3];
    const float* w_inp    = (const float*)d_in[4];
    const float* ln1_s    = (const float*)d_in[5];
    const float* ln1_b    = (const float*)d_in[6];
    const float* wq       = (const float*)d_in[7];
    const float* wk       = (const float*)d_in[8];
    const float* wv       = (const float*)d_in[9];
    const float* wo       = (const float*)d_in[10];
    const float* ln2_s    = (const float*)d_in[11];
    const float* ln2_b    = (const float*)d_in[12];
    const float* w1       = (const float*)d_in[13];
    const float* b1       = (const float*)d_in[14];
    const float* w2       = (const float*)d_in[15];
    const float* b2       = (const float*)d_in[16];
    float* out = (float*)d_out;
    char* ws = (char*)d_ws;
    const size_t MB = 1u << 20;
    u16*   INb  = (u16*)(ws + 0 * MB);
    u16*   WIt  = (u16*)(ws + 16 * MB);
    u16*   WQt  = (u16*)(ws + 18 * MB);
    u16*   WKt  = (u16*)(ws + 20 * MB);
    u16*   WVt  = (u16*)(ws + 22 * MB);
    u16*   WOt  = (u16*)(ws + 24 * MB);
    u16*   W1t  = (u16*)(ws + 26 * MB);
    u16*   W2t  = (u16*)(ws + 34 * MB);
    u16*   Qb   = (u16*)(ws + 48 * MB);
    u16*   HID  = (u16*)(ws + 48 * MB);
    float* STU  = (float*)(ws + 80 * MB);
    u16*   XN   = (u16*)(ws + 112 * MB);
    u16*   Ab   = (u16*)(ws + 112 * MB);
    float* Fv   = (float*)(ws + 128 * MB);
    u16*   Kb   = (u16*)(ws + 128 * MB);
    float* Xb   = (float*)(ws + 128 * MB);
    u16*   Vb   = (u16*)(ws + 160 * MB);
    u16*   YN   = (u16*)(ws + 160 * MB);
    float* XI   = (float*)(ws + 176 * MB);

    const int M = B_ * L_;

    cast_bf16<<<(M * D_ / 4 + 255) / 256, 256, 0, stream>>>(inputs, INb);
    cast_T<<<dim3(D_ / 32, D_ / 32), 256, 0, stream>>>(w_inp, WIt, D_, D_);
    cast_T<<<dim3(D_ / 32, D_ / 32), 256, 0, stream>>>(wq, WQt, D_, D_);
    cast_T<<<dim3(D_ / 32, D_ / 32), 256, 0, stream>>>(wk, WKt, D_, D_);
    cast_T<<<dim3(D_ / 32, D_ / 32), 256, 0, stream>>>(wv, WVt, D_, D_);
    cast_T<<<dim3(D_ / 32, D_ / 32), 256, 0, stream>>>(wo, WOt, D_, D_);
    cast_T<<<dim3(MLP_ / 32, D_ / 32), 256, 0, stream>>>(w1, W1t, D_, MLP_);
    cast_T<<<dim3(D_ / 32, MLP_ / 32), 256, 0, stream>>>(w2, W2t, MLP_, D_);

    filters_kernel<<<dim3(L_, D_ / 256), 256, 0, stream>>>(eig_vals, eig_vecs, w_filt, Fv);

    gemm_bf16<<<dim3(D_ / 128, M / 128), 256, 0, stream>>>(
        INb, WIt, XI, nullptr, M, D_, D_, 1.f, nullptr, nullptr, 0);
    conv_k<<<dim3(16, D_ / 64, B_), 256, 0, stream>>>(Fv, XI, STU);
    layernorm_bf16<<<M, 256, 0, stream>>>(STU, ln1_s, ln1_b, XN);
    gemm_bf16<<<dim3(D_ / 128, M / 128), 256, 0, stream>>>(
        XN, WQt, nullptr, Qb, M, D_, D_, 0.125f, nullptr, nullptr, 0);
    gemm_bf16<<<dim3(D_ / 128, M / 128), 256, 0, stream>>>(
        XN, WKt, nullptr, Kb, M, D_, D_, 1.f, nullptr, nullptr, 0);
    gemm_bf16<<<dim3(D_ / 128, M / 128), 256, 0, stream>>>(
        XN, WVt, nullptr, Vb, M, D_, D_, 1.f, nullptr, nullptr, 0);
    attn_mfma<<<dim3(L_ / 64, B_ * H_), 256, 0, stream>>>(Qb, Kb, Vb, Ab);
    gemm_bf16<<<dim3(D_ / 128, M / 128), 256, 0, stream>>>(
        Ab, WOt, Xb, nullptr, M, D_, D_, 1.f, nullptr, STU, 0);
    layernorm_bf16<<<M, 256, 0, stream>>>(Xb, ln2_s, ln2_b, YN);
    gemm_bf16<<<dim3(MLP_ / 128, M / 128), 256, 0, stream>>>(
        YN, W1t, nullptr, HID, M, MLP_, D_, 1.f, b1, nullptr, 1);
    gemm_bf16<<<dim3(D_ / 128, M / 128), 256, 0, stream>>>(
        HID, W2t, out, nullptr, M, D_, MLP_, 1.f, b2, Xb, 0);
}

// Round 5
// 1233.435 us; speedup vs baseline: 4.0669x; 1.0923x over previous
//
#include <hip/hip_runtime.h>
#include <math.h>

#define B_ 4
#define L_ 2048
#define D_ 1024
#define H_ 16
#define HD_ 64
#define K_ 24
#define MLP_ 4096

typedef unsigned short u16;
typedef short s16x8 __attribute__((ext_vector_type(8)));
typedef float fx4 __attribute__((ext_vector_type(4)));

__device__ __forceinline__ u16 f2bf(float f) {
    unsigned u = __float_as_uint(f);
    unsigned r = (u + 0x7fff + ((u >> 16) & 1)) >> 16;
    return (u16)r;
}

__device__ __forceinline__ float gelu_t(float x) {
    float u = 0.7978845608028654f * (x + 0.044715f * x * x * x);
    return x / (1.f + __expf(-2.f * u));
}

__device__ __forceinline__ void gload_lds16(const void* g, void* l) {
    __builtin_amdgcn_global_load_lds(
        (const __attribute__((address_space(1))) unsigned int*)g,
        (__attribute__((address_space(3))) unsigned int*)l, 16, 0, 0);
}

// ---------------------------------------------------------------------------
// filters[l,d] = sum_k eig_vecs[l,k] * eig_vals[k]^0.25 * w_filters[k,d]
// ---------------------------------------------------------------------------
__global__ void filters_kernel(const float* __restrict__ eig_vals,
                               const float* __restrict__ eig_vecs,
                               const float* __restrict__ w_filters,
                               float* __restrict__ out) {
    int l = blockIdx.x;
    int d = blockIdx.y * 256 + threadIdx.x;
    __shared__ float r[K_];
    if (threadIdx.x < K_) {
        float ev = eig_vals[threadIdx.x];
        r[threadIdx.x] = eig_vecs[l * K_ + threadIdx.x] * powf(ev, 0.25f);
    }
    __syncthreads();
    float acc = 0.f;
#pragma unroll
    for (int k = 0; k < K_; k++) acc += r[k] * w_filters[k * D_ + d];
    out[(size_t)l * D_ + d] = acc;
}

// ---------------------------------------------------------------------------
__global__ __launch_bounds__(256) void cast_bf16(const float* __restrict__ in,
                                                 u16* __restrict__ out) {
    int i = blockIdx.x * 256 + threadIdx.x;
    float4 v = ((const float4*)in)[i];
    ushort4 o;
    o.x = f2bf(v.x); o.y = f2bf(v.y); o.z = f2bf(v.z); o.w = f2bf(v.w);
    ((ushort4*)out)[i] = o;
}

// ---------------------------------------------------------------------------
// fp32 [R][C] -> bf16 [C][R] transpose-cast (32x32 LDS tile)
// ---------------------------------------------------------------------------
__global__ __launch_bounds__(256) void cast_T(const float* __restrict__ in,
                                              u16* __restrict__ out, int R, int C) {
    __shared__ float t[32][33];
    int c0 = blockIdx.x * 32, r0 = blockIdx.y * 32;
    int tx = threadIdx.x & 31, ty = threadIdx.x >> 5;
#pragma unroll
    for (int p = 0; p < 4; p++)
        t[ty + p * 8][tx] = in[(size_t)(r0 + ty + p * 8) * C + c0 + tx];
    __syncthreads();
#pragma unroll
    for (int p = 0; p < 4; p++)
        out[(size_t)(c0 + ty + p * 8) * R + r0 + tx] = f2bf(t[tx][ty + p * 8]);
}

// ---------------------------------------------------------------------------
// bf16 MFMA GEMM: out = act(alpha * A @ Bt^T + bias) + resid
// qcols: columns < qcols get alpha*0.125 (fused-QKV Q-scale)
// ---------------------------------------------------------------------------
__global__ __launch_bounds__(256) void gemm_bf16(
    const u16* __restrict__ A, const u16* __restrict__ Bt,
    float* __restrict__ C, u16* __restrict__ Cb,
    int M, int N, int K, float alpha,
    const float* __restrict__ bias, const float* __restrict__ resid, int act,
    int qcols) {
    __shared__ u16 As[4][128][8];
    __shared__ u16 Bs[4][128][8];
    int tid = threadIdx.x;
    int wid = tid >> 6, lane = tid & 63;
    int bm = blockIdx.y * 128, bn = blockIdx.x * 128;
    int wm = (wid >> 1) * 64, wn = (wid & 1) * 64;
    int q = lane >> 4, r = lane & 15;

    const u16* gA0 = A + (size_t)(bm + lane) * K + wid * 8;
    const u16* gA1 = gA0 + (size_t)64 * K;
    const u16* gB0 = Bt + (size_t)(bn + lane) * K + wid * 8;
    const u16* gB1 = gB0 + (size_t)64 * K;
    u16* lA0 = &As[wid][0][0];
    u16* lA1 = &As[wid][64][0];
    u16* lB0 = &Bs[wid][0][0];
    u16* lB1 = &Bs[wid][64][0];
    const u16* pa = &As[q][wm + r][0];
    const u16* pb = &Bs[q][wn + r][0];

    fx4 acc[4][4];
#pragma unroll
    for (int i = 0; i < 4; i++)
#pragma unroll
        for (int j = 0; j < 4; j++) acc[i][j] = (fx4){0.f, 0.f, 0.f, 0.f};

    for (int k0 = 0; k0 < K; k0 += 32) {
        if (k0) __syncthreads();
        gload_lds16(gA0 + k0, lA0);
        gload_lds16(gA1 + k0, lA1);
        gload_lds16(gB0 + k0, lB0);
        gload_lds16(gB1 + k0, lB1);
        __syncthreads();
        s16x8 a[4], b[4];
#pragma unroll
        for (int i = 0; i < 4; i++) a[i] = *(const s16x8*)(pa + i * 128);
#pragma unroll
        for (int j = 0; j < 4; j++) b[j] = *(const s16x8*)(pb + j * 128);
#pragma unroll
        for (int i = 0; i < 4; i++)
#pragma unroll
            for (int j = 0; j < 4; j++)
                acc[i][j] = __builtin_amdgcn_mfma_f32_16x16x32_bf16(
                    a[i], b[j], acc[i][j], 0, 0, 0);
    }

#pragma unroll
    for (int i = 0; i < 4; i++) {
        int row0 = bm + wm + i * 16 + q * 4;
#pragma unroll
        for (int j = 0; j < 4; j++) {
            int col = bn + wn + j * 16 + r;
            float a2 = (col < qcols) ? alpha * 0.125f : alpha;
            float bv = bias ? bias[col] : 0.f;
#pragma unroll
            for (int reg = 0; reg < 4; reg++) {
                float v = a2 * acc[i][j][reg] + bv;
                if (act) v = gelu_t(v);
                size_t idx = (size_t)(row0 + reg) * N + col;
                if (resid) v += resid[idx];
                if (C) C[idx] = v;
                else Cb[idx] = f2bf(v);
            }
        }
    }
}

// ---------------------------------------------------------------------------
// Causal per-channel conv: out[b,l,d] = sum_{t=0..l} F[t,d]*XI[b,l-t,d]
// Balanced pairing (tiles i & 31-i). Layouts (stride%8==4 -> b128 reads hit
// the uniform 8-access/bank minimum; lane->d staging stores are b128 uniform):
//   xs[d][col]  stride 132, cols 0..127 = j in [jb, jb+127]
//   ft[d][t]    stride 68  (transposed filter tile)
// Inner loop: 20-reg circular window, fully unrolled -> no register shifts.
// ---------------------------------------------------------------------------
__global__ __launch_bounds__(256) void conv_k(const float* __restrict__ F,
                                              const float* __restrict__ XI,
                                              float* __restrict__ OUT) {
    int d0 = blockIdx.y * 64, b = blockIdx.z;
    __shared__ float xs[64][132];
    __shared__ float ft[64][68];
    int tid = threadIdx.x;
    int dd = tid & 63;
    int jg = tid >> 6;
    int L0 = jg * 16;
    const float* xib = XI + (size_t)b * L_ * D_;

#pragma unroll 1
    for (int half = 0; half < 2; half++) {
        int lt = half ? (31 - blockIdx.x) : blockIdx.x;
        int l0 = lt * 64;
        float acc[16];
#pragma unroll
        for (int i = 0; i < 16; i++) acc[i] = 0.f;

        for (int t0 = 0; t0 <= l0; t0 += 64) {
            int jb = l0 - t0 - 63;
            // stage filters transposed: ft[d][t]
#pragma unroll
            for (int mm = 0; mm < 4; mm++) {
                int t4 = (jg + 4 * mm) * 4;
                float4 v;
                v.x = F[(size_t)(t0 + t4 + 0) * D_ + d0 + dd];
                v.y = F[(size_t)(t0 + t4 + 1) * D_ + d0 + dd];
                v.z = F[(size_t)(t0 + t4 + 2) * D_ + d0 + dd];
                v.w = F[(size_t)(t0 + t4 + 3) * D_ + d0 + dd];
                *(float4*)&ft[dd][t4] = v;
            }
            // stage xi window: xs[d][c] = XI[jb+c, d]  (zero outside [0,L))
            if (jb >= 0 && jb + 127 < L_) {
#pragma unroll
                for (int mm = 0; mm < 8; mm++) {
                    int c0 = (jg + 4 * mm) * 4;
                    float4 v;
                    v.x = xib[(size_t)(jb + c0 + 0) * D_ + d0 + dd];
                    v.y = xib[(size_t)(jb + c0 + 1) * D_ + d0 + dd];
                    v.z = xib[(size_t)(jb + c0 + 2) * D_ + d0 + dd];
                    v.w = xib[(size_t)(jb + c0 + 3) * D_ + d0 + dd];
                    *(float4*)&xs[dd][c0] = v;
                }
            } else {
#pragma unroll
                for (int mm = 0; mm < 8; mm++) {
                    int c0 = (jg + 4 * mm) * 4;
                    float4 v;
#pragma unroll
                    for (int k = 0; k < 4; k++) {
                        int j = jb + c0 + k;
                        ((float*)&v)[k] = (j >= 0 && j < L_)
                            ? xib[(size_t)j * D_ + d0 + dd] : 0.f;
                    }
                    *(float4*)&xs[dd][c0] = v;
                }
            }
            __syncthreads();

            float W[20];
            {
                float4 a0 = *(const float4*)&xs[dd][L0];
                float4 a1 = *(const float4*)&xs[dd][L0 + 4];
                float4 a2 = *(const float4*)&xs[dd][L0 + 8];
                float4 a3 = *(const float4*)&xs[dd][L0 + 12];
                W[0] = a0.x; W[1] = a0.y; W[2] = a0.z; W[3] = a0.w;
                W[4] = a1.x; W[5] = a1.y; W[6] = a1.z; W[7] = a1.w;
                W[8] = a2.x; W[9] = a2.y; W[10] = a2.z; W[11] = a2.w;
                W[12] = a3.x; W[13] = a3.y; W[14] = a3.z; W[15] = a3.w;
            }
#pragma unroll
            for (int s = 0; s < 16; s++) {
                const int base = (4 * s) % 20;
                float4 nx = *(const float4*)&xs[dd][L0 + 16 + 4 * s];
                W[(base + 16) % 20] = nx.x;
                W[(base + 17) % 20] = nx.y;
                W[(base + 18) % 20] = nx.z;
                W[(base + 19) % 20] = nx.w;
                float4 f4 = *(const float4*)&ft[dd][60 - 4 * s];
                float f0 = f4.w, f1 = f4.z, f2 = f4.y, f3 = f4.x;
#pragma unroll
                for (int i = 0; i < 16; i++) acc[i] += f0 * W[(base + i) % 20];
#pragma unroll
                for (int i = 0; i < 16; i++) acc[i] += f1 * W[(base + i + 1) % 20];
#pragma unroll
                for (int i = 0; i < 16; i++) acc[i] += f2 * W[(base + i + 2) % 20];
#pragma unroll
                for (int i = 0; i < 16; i++) acc[i] += f3 * W[(base + i + 3) % 20];
            }
            __syncthreads();
        }
#pragma unroll
        for (int i = 0; i < 16; i++)
            OUT[((size_t)b * L_ + l0 + L0 + i) * D_ + d0 + dd] = acc[i];
    }
}

// ---------------------------------------------------------------------------
// LayerNorm -> bf16 out (row = 1024), eps 1e-6
// ---------------------------------------------------------------------------
__global__ __launch_bounds__(256) void layernorm_bf16(const float* __restrict__ x,
                                                      const float* __restrict__ scale,
                                                      const float* __restrict__ bias,
                                                      u16* __restrict__ y) {
    size_t row = blockIdx.x;
    int tid = threadIdx.x;
    const float4 v = *(const float4*)&x[row * D_ + tid * 4];
    float s = v.x + v.y + v.z + v.w;
    float q = v.x * v.x + v.y * v.y + v.z * v.z + v.w * v.w;
#pragma unroll
    for (int off = 32; off >= 1; off >>= 1) {
        s += __shfl_xor(s, off, 64);
        q += __shfl_xor(q, off, 64);
    }
    __shared__ float ss[4], sq[4];
    int w = tid >> 6;
    if ((tid & 63) == 0) { ss[w] = s; sq[w] = q; }
    __syncthreads();
    s = ss[0] + ss[1] + ss[2] + ss[3];
    q = sq[0] + sq[1] + sq[2] + sq[3];
    float mean = s * (1.f / D_);
    float var = q * (1.f / D_) - mean * mean;
    float r = rsqrtf(var + 1e-6f);
    const float4 sc = *(const float4*)&scale[tid * 4];
    const float4 bi = *(const float4*)&bias[tid * 4];
    ushort4 o;
    o.x = f2bf((v.x - mean) * r * sc.x + bi.x);
    o.y = f2bf((v.y - mean) * r * sc.y + bi.y);
    o.z = f2bf((v.z - mean) * r * sc.z + bi.z);
    o.w = f2bf((v.w - mean) * r * sc.w + bi.w);
    *(ushort4*)&y[row * D_ + tid * 4] = o;
}

// ---------------------------------------------------------------------------
// MFMA flash attention, TQ=128. Q,K,V are column slices of the fused
// [B*L, 3072] bf16 QKV buffer (stride 3072); Q pre-scaled. Out bf16 [M,1024].
// ps overlays qs (aq hoisted to regs; each wave only touches its own rows).
// ---------------------------------------------------------------------------
__global__ __launch_bounds__(256) void attn_mfma(const u16* __restrict__ Qg,
                                                 const u16* __restrict__ Kg,
                                                 const u16* __restrict__ Vg,
                                                 u16* __restrict__ Og) {
    const int QSTR = 3072;
    int q0 = blockIdx.x * 128;
    int b = blockIdx.y >> 4, h = blockIdx.y & 15;
    __shared__ __align__(16) u16 qs[128 * 72];
    __shared__ __align__(16) u16 ks[64 * 72];
    __shared__ __align__(16) u16 vt[64 * 72];   // V^T: [hd][s]
    int tid = threadIdx.x;
    int w = tid >> 6, lane = tid & 63;
    int quad = lane >> 4, l15 = lane & 15;
    const size_t base = (size_t)b * L_ * QSTR + h * HD_;

    // stage Q tile (once)
#pragma unroll
    for (int i = tid; i < 128 * 8; i += 256) {
        int r = i >> 3, c = i & 7;
        *(uint4*)&qs[r * 72 + c * 8] =
            *(const uint4*)&Qg[base + (size_t)(q0 + r) * QSTR + c * 8];
    }
    __syncthreads();
    s16x8 aq[2][2];
#pragma unroll
    for (int mi = 0; mi < 2; mi++)
#pragma unroll
        for (int kb = 0; kb < 2; kb++)
            aq[mi][kb] = *(const s16x8*)&qs[(w * 32 + mi * 16 + l15) * 72 + kb * 32 + quad * 8];

    float m[2][4], lsum[2][4];
    fx4 o[2][4];
#pragma unroll
    for (int mi = 0; mi < 2; mi++)
#pragma unroll
        for (int i = 0; i < 4; i++) {
            m[mi][i] = -1e30f; lsum[mi][i] = 0.f;
            o[mi][i] = (fx4){0.f, 0.f, 0.f, 0.f};
        }
    u16* psw = qs + w * 32 * 72;   // wave-private (rows this wave hoisted)

    for (int s0 = 0; s0 < L_; s0 += 64) {
        __syncthreads();
#pragma unroll
        for (int i = tid; i < 64 * 8; i += 256) {
            int r = i >> 3, c = i & 7;
            *(uint4*)&ks[r * 72 + c * 8] =
                *(const uint4*)&Kg[base + (size_t)(s0 + r) * QSTR + c * 8];
        }
        {
            int s = lane;
#pragma unroll
            for (int it = 0; it < 2; it++) {
                int hd0 = w * 8 + it * 32;
                uint4 v = *(const uint4*)&Vg[base + (size_t)(s0 + s) * QSTR + hd0];
                u16 tmp[8];
                *(uint4*)tmp = v;
#pragma unroll
                for (int j = 0; j < 8; j++) vt[(hd0 + j) * 72 + s] = tmp[j];
            }
        }
        __syncthreads();

        // S = Q K^T : per-wave 32q x 64s
        fx4 sv[2][4];
#pragma unroll
        for (int mi = 0; mi < 2; mi++)
#pragma unroll
            for (int nt = 0; nt < 4; nt++) sv[mi][nt] = (fx4){0.f, 0.f, 0.f, 0.f};
#pragma unroll
        for (int kb = 0; kb < 2; kb++)
#pragma unroll
            for (int nt = 0; nt < 4; nt++) {
                s16x8 bk = *(const s16x8*)&ks[(nt * 16 + l15) * 72 + kb * 32 + quad * 8];
#pragma unroll
                for (int mi = 0; mi < 2; mi++)
                    sv[mi][nt] = __builtin_amdgcn_mfma_f32_16x16x32_bf16(
                        aq[mi][kb], bk, sv[mi][nt], 0, 0, 0);
            }

        // online softmax per mi
#pragma unroll
        for (int mi = 0; mi < 2; mi++) {
            float mx[4], cor[4], rs[4];
#pragma unroll
            for (int reg = 0; reg < 4; reg++)
                mx[reg] = fmaxf(fmaxf(sv[mi][0][reg], sv[mi][1][reg]),
                                fmaxf(sv[mi][2][reg], sv[mi][3][reg]));
#pragma unroll
            for (int off = 8; off >= 1; off >>= 1)
#pragma unroll
                for (int reg = 0; reg < 4; reg++)
                    mx[reg] = fmaxf(mx[reg], __shfl_xor(mx[reg], off, 16));
#pragma unroll
            for (int reg = 0; reg < 4; reg++) {
                float mn = fmaxf(m[mi][reg], mx[reg]);
                cor[reg] = __expf(m[mi][reg] - mn);
                m[mi][reg] = mn;
                rs[reg] = 0.f;
            }
#pragma unroll
            for (int nt = 0; nt < 4; nt++)
#pragma unroll
                for (int reg = 0; reg < 4; reg++) {
                    float p = __expf(sv[mi][nt][reg] - m[mi][reg]);
                    sv[mi][nt][reg] = p;
                    rs[reg] += p;
                }
#pragma unroll
            for (int off = 8; off >= 1; off >>= 1)
#pragma unroll
                for (int reg = 0; reg < 4; reg++)
                    rs[reg] += __shfl_xor(rs[reg], off, 16);
#pragma unroll
            for (int reg = 0; reg < 4; reg++)
                lsum[mi][reg] = lsum[mi][reg] * cor[reg] + rs[reg];
#pragma unroll
            for (int nt = 0; nt < 4; nt++) {
                fx4 on = o[mi][nt];
                on[0] *= cor[0]; on[1] *= cor[1]; on[2] *= cor[2]; on[3] *= cor[3];
                o[mi][nt] = on;
            }
            // P -> wave-private LDS (A-operand source layout)
#pragma unroll
            for (int nt = 0; nt < 4; nt++)
#pragma unroll
                for (int reg = 0; reg < 4; reg++)
                    psw[(mi * 16 + quad * 4 + reg) * 72 + nt * 16 + l15] =
                        f2bf(sv[mi][nt][reg]);
        }
        // PV: O += P V
#pragma unroll
        for (int kb = 0; kb < 2; kb++) {
            s16x8 ap[2];
#pragma unroll
            for (int mi = 0; mi < 2; mi++)
                ap[mi] = *(const s16x8*)&psw[(mi * 16 + l15) * 72 + kb * 32 + quad * 8];
#pragma unroll
            for (int nt = 0; nt < 4; nt++) {
                s16x8 bv = *(const s16x8*)&vt[(nt * 16 + l15) * 72 + kb * 32 + quad * 8];
#pragma unroll
                for (int mi = 0; mi < 2; mi++)
                    o[mi][nt] = __builtin_amdgcn_mfma_f32_16x16x32_bf16(
                        ap[mi], bv, o[mi][nt], 0, 0, 0);
            }
        }
    }
    // epilogue: O / l -> bf16 out [M,1024]
    const size_t baseo = (size_t)b * L_ * 1024 + h * HD_;
#pragma unroll
    for (int mi = 0; mi < 2; mi++)
#pragma unroll
        for (int reg = 0; reg < 4; reg++) {
            float inv = 1.f / lsum[mi][reg];
            size_t row = baseo +
                (size_t)(q0 + w * 32 + mi * 16 + quad * 4 + reg) * 1024;
#pragma unroll
            for (int nt = 0; nt < 4; nt++)
                Og[row + nt * 16 + l15] = f2bf(o[mi][nt][reg] * inv);
        }
}

// ---------------------------------------------------------------------------
extern "C" void kernel_launch(void* const* d_in, const int* in_sizes, int n_in,
                              void* d_out, int out_size, void* d_ws, size_t ws_size,
                              hipStream_t stream) {
    const float* inputs   = (const float*)d_in[0];
    const float* eig_vals = (const float*)d_in[1];
    const float* eig_vecs = (const float*)d_in[2];
    const float* w_filt   = (const float*)d_in[3];
    const float* w_inp    = (const float*)d_in[4];
    const float* ln1_s    = (const float*)d_in[5];
    const float* ln1_b    = (const float*)d_in[6];
    const float* wq       = (const float*)d_in[7];
    const float* wk       = (const float*)d_in[8];
    const float* wv       = (const float*)d_in[9];
    const float* wo       = (const float*)d_in[10];
    const float* ln2_s    = (const float*)d_in[11];
    const float* ln2_b    = (const float*)d_in[12];
    const float* w1       = (const float*)d_in[13];
    const float* b1       = (const float*)d_in[14];
    const float* w2       = (const float*)d_in[15];
    const float* b2       = (const float*)d_in[16];
    float* out = (float*)d_out;
    char* ws = (char*)d_ws;
    const size_t MB = 1u << 20;
    // Region plan (peak 192MB):
    //   0-16  : INb bf16                 [dead after XI gemm]
    //  16-42  : weights: WIt@16, WQKVt@18(6MB), WOt@24, W1t@26, W2t@34
    //  48-80  : XI fp32                  [dead after conv]
    //  48-112 : HID bf16 (MLP phase; XI+STU dead by then)
    //  80-112 : STU fp32                 [dead after WO gemm]
    // 112-128 : XN bf16                  [dead after QKV gemm]
    // 128-176 : QKV bf16 fused [M,3072]  [dead after attn]
    // 128-160 : Xb fp32 (after attn)
    // 160-176 : YN bf16 (after WO gemm)
    // 176-184 : Fv fp32                  [dead after conv]
    // 176-192 : Ab bf16 (after attn)     [dead after WO gemm]
    u16*   INb   = (u16*)(ws + 0 * MB);
    u16*   WIt   = (u16*)(ws + 16 * MB);
    u16*   WQKVt = (u16*)(ws + 18 * MB);
    u16*   WOt   = (u16*)(ws + 24 * MB);
    u16*   W1t   = (u16*)(ws + 26 * MB);
    u16*   W2t   = (u16*)(ws + 34 * MB);
    float* XI    = (float*)(ws + 48 * MB);
    u16*   HID   = (u16*)(ws + 48 * MB);
    float* STU   = (float*)(ws + 80 * MB);
    u16*   XN    = (u16*)(ws + 112 * MB);
    u16*   QKV   = (u16*)(ws + 128 * MB);
    float* Xb    = (float*)(ws + 128 * MB);
    u16*   YN    = (u16*)(ws + 160 * MB);
    float* Fv    = (float*)(ws + 176 * MB);
    u16*   Ab    = (u16*)(ws + 176 * MB);

    const int M = B_ * L_;

    cast_bf16<<<(M * D_ / 4 + 255) / 256, 256, 0, stream>>>(inputs, INb);
    cast_T<<<dim3(D_ / 32, D_ / 32), 256, 0, stream>>>(w_inp, WIt, D_, D_);
    cast_T<<<dim3(D_ / 32, D_ / 32), 256, 0, stream>>>(wq, WQKVt + 0 * D_ * D_, D_, D_);
    cast_T<<<dim3(D_ / 32, D_ / 32), 256, 0, stream>>>(wk, WQKVt + 1 * D_ * D_, D_, D_);
    cast_T<<<dim3(D_ / 32, D_ / 32), 256, 0, stream>>>(wv, WQKVt + 2 * D_ * D_, D_, D_);
    cast_T<<<dim3(D_ / 32, D_ / 32), 256, 0, stream>>>(wo, WOt, D_, D_);
    cast_T<<<dim3(MLP_ / 32, D_ / 32), 256, 0, stream>>>(w1, W1t, D_, MLP_);
    cast_T<<<dim3(D_ / 32, MLP_ / 32), 256, 0, stream>>>(w2, W2t, MLP_, D_);

    filters_kernel<<<dim3(L_, D_ / 256), 256, 0, stream>>>(eig_vals, eig_vecs, w_filt, Fv);

    gemm_bf16<<<dim3(D_ / 128, M / 128), 256, 0, stream>>>(
        INb, WIt, XI, nullptr, M, D_, D_, 1.f, nullptr, nullptr, 0, 0);
    conv_k<<<dim3(16, D_ / 64, B_), 256, 0, stream>>>(Fv, XI, STU);
    layernorm_bf16<<<M, 256, 0, stream>>>(STU, ln1_s, ln1_b, XN);
    // fused QKV (cols<1024 get the 1/sqrt(hd) Q-scale)
    gemm_bf16<<<dim3(3 * D_ / 128, M / 128), 256, 0, stream>>>(
        XN, WQKVt, nullptr, QKV, M, 3 * D_, D_, 1.f, nullptr, nullptr, 0, D_);
    attn_mfma<<<dim3(L_ / 128, B_ * H_), 256, 0, stream>>>(
        QKV, QKV + D_, QKV + 2 * D_, Ab);
    gemm_bf16<<<dim3(D_ / 128, M / 128), 256, 0, stream>>>(
        Ab, WOt, Xb, nullptr, M, D_, D_, 1.f, nullptr, STU, 0, 0);
    layernorm_bf16<<<M, 256, 0, stream>>>(Xb, ln2_s, ln2_b, YN);
    gemm_bf16<<<dim3(MLP_ / 128, M / 128), 256, 0, stream>>>(
        YN, W1t, nullptr, HID, M, MLP_, D_, 1.f, b1, nullptr, 1, 0);
    gemm_bf16<<<dim3(D_ / 128, M / 128), 256, 0, stream>>>(
        HID, W2t, out, nullptr, M, D_, MLP_, 1.f, b2, Xb, 0, 0);
}